// Round 4
// baseline (10188.954 us; speedup 1.0000x reference)
//
#include <hip/hip_runtime.h>

// ---------------------------------------------------------------------------
// TransformerAgent (Performer/FAVOR+ encoder), MI355X gfx950.
// Round 4: fp32 inputs AND fp32 output (reference dtype is float32; the
// "bf16" in the test label is the comparison space, not the buffer dtype).
// Workspace: exactly 4 x 64 MiB = 256 MiB (KV aliases X, FF hidden aliases Qb).
// B=16, L=4096(=1+4095), HID=256, NH=8, DH=32, FF=1024, NL=4, ACT=32
// ---------------------------------------------------------------------------

typedef unsigned short bf16_t;

#define NB 16
#define LSEQ 4096
#define MROWS (NB * LSEQ)      // 65536
#define HIDD 256
#define NHEAD 8
#define DHEAD 32
#define FFD 1024
#define NLAY 4
#define KEPS_F 1e-3f
#define LNEPS_F 1e-6f
#define KV_ELEMS (NB * NHEAD * 32 * 33)   // 135168

// ---------------------------------------------------------------------------
// Embed: X[b,0,:] = resets? 0 : hidden ; X[b,l,:] = ins[b,l-1,:]@embW + embb
// ---------------------------------------------------------------------------
__global__ __launch_bounds__(256) void embed_kernel(
    const float* __restrict__ hidden, const float* __restrict__ ins,
    const int* __restrict__ resets, const float* __restrict__ embW,
    const float* __restrict__ embb, float* __restrict__ X)
{
    const int row = blockIdx.x;
    const int b = row >> 12, l = row & (LSEQ - 1);
    const int j = threadIdx.x;
    if (l == 0) {
        float v = resets[b] ? 0.f : hidden[b * HIDD + j];
        X[(size_t)row * HIDD + j] = v;
        return;
    }
    __shared__ float si[128];
    const float* ir = ins + ((size_t)b * 4095 + (l - 1)) * 128;
    if (j < 128) si[j] = ir[j];
    __syncthreads();
    float acc = embb[j];
#pragma unroll 4
    for (int k = 0; k < 128; k++)
        acc = fmaf(si[k], embW[k * HIDD + j], acc);
    X[(size_t)row * HIDD + j] = acc;
}

// ---------------------------------------------------------------------------
// Tiled SGEMM: C[M,N] = act(A[M,K] @ W[K,N] + bias[N])
// A, W, C fp32 row-major. M%128==0, N%128==0, K%8==0.
// MODE: 0 = none, 1 = relu.  128x128 tile, 256 thr, 8x8 per thread.
// ---------------------------------------------------------------------------
template <int MODE>
__global__ __launch_bounds__(256) void gemm_f32(
    const float* __restrict__ A, const float* __restrict__ W,
    const float* __restrict__ bias, float* __restrict__ C,
    int M, int N, int K)
{
    constexpr int BK = 8;
    __shared__ float As[BK][128];
    __shared__ float Bs[BK][128];
    const int tid = threadIdx.x;
    const int bm = blockIdx.y * 128, bn = blockIdx.x * 128;
    const int tx = tid & 15, ty = tid >> 4;
    const int ar = tid >> 1, akq = (tid & 1) * 4;       // A: 128 rows x 8 k
    const int bkr = tid >> 5, bn4 = (tid & 31) * 4;     // W: 8 k x 128 n
    const float* Aptr = A + (size_t)(bm + ar) * K + akq;
    const float* Wptr = W + (size_t)bkr * N + bn + bn4;

    float acc[8][8];
#pragma unroll
    for (int i = 0; i < 8; i++)
#pragma unroll
        for (int j = 0; j < 8; j++) acc[i][j] = 0.f;

    for (int k0 = 0; k0 < K; k0 += BK) {
        float4 av = *(const float4*)(Aptr + k0);
        float4 wv = *(const float4*)(Wptr + (size_t)k0 * N);
        As[akq + 0][ar] = av.x;
        As[akq + 1][ar] = av.y;
        As[akq + 2][ar] = av.z;
        As[akq + 3][ar] = av.w;
        Bs[bkr][bn4 + 0] = wv.x;
        Bs[bkr][bn4 + 1] = wv.y;
        Bs[bkr][bn4 + 2] = wv.z;
        Bs[bkr][bn4 + 3] = wv.w;
        __syncthreads();
#pragma unroll
        for (int k = 0; k < BK; k++) {
            float a[8], bb[8];
            *(float4*)&a[0]  = *(const float4*)&As[k][ty * 8];
            *(float4*)&a[4]  = *(const float4*)&As[k][ty * 8 + 4];
            *(float4*)&bb[0] = *(const float4*)&Bs[k][tx * 8];
            *(float4*)&bb[4] = *(const float4*)&Bs[k][tx * 8 + 4];
#pragma unroll
            for (int i = 0; i < 8; i++)
#pragma unroll
                for (int j = 0; j < 8; j++)
                    acc[i][j] = fmaf(a[i], bb[j], acc[i][j]);
        }
        __syncthreads();
    }

#pragma unroll
    for (int i = 0; i < 8; i++) {
        size_t r = (size_t)(bm + ty * 8 + i);
        float* crow = C + r * N + bn + tx * 8;
#pragma unroll
        for (int j = 0; j < 8; j++) {
            float v = acc[i][j] + bias[bn + tx * 8 + j];
            if (MODE == 1) v = fmaxf(v, 0.f);
            crow[j] = v;
        }
    }
}

// ---------------------------------------------------------------------------
// Zero the KV accumulator (graph-capture-safe replacement for memset)
// ---------------------------------------------------------------------------
__global__ __launch_bounds__(256) void zero_kv(float* __restrict__ KV)
{
    int i = blockIdx.x * 256 + threadIdx.x;
    if (i < KV_ELEMS) KV[i] = 0.f;
}

// ---------------------------------------------------------------------------
// FAVOR state: KV[b,h,m,d] = sum_l kp[b,l,h,m] * V_ext[b,l,h,d]
//   kp = relu(k)+eps ; V_ext = [v | 1]  (d = 33 columns, col 32 = kp-sum)
// grid (B*NH, 8 splits of L), atomicAdd fp32 into KV (pre-zeroed)
// ---------------------------------------------------------------------------
#define LSPLIT 8
#define LCH (LSEQ / LSPLIT)    // 512

__global__ __launch_bounds__(256) void kv_kernel(
    const float* __restrict__ Km, const float* __restrict__ Vm,
    float* __restrict__ KV)
{
    const int bh = blockIdx.x;
    const int b = bh >> 3, h = bh & 7;
    const int l0 = blockIdx.y * LCH;
    const int tid = threadIdx.x;
    __shared__ float kp[32][33];
    __shared__ float vv[32][33];

    float acc[5] = {0.f, 0.f, 0.f, 0.f, 0.f};
    int om[5], od[5];
#pragma unroll
    for (int i = 0; i < 5; i++) {
        int o = tid + i * 256;
        om[i] = (o < 32 * 33) ? (o / 33) : 0;
        od[i] = (o < 32 * 33) ? (o % 33) : 0;
    }
    const bool has5 = (tid < (33 * 32 - 1024));

    for (int c = 0; c < LCH; c += 32) {
        for (int e = tid; e < 1024; e += 256) {
            int r = e >> 5, cc = e & 31;
            size_t base = ((size_t)(b * LSEQ + l0 + c + r)) * HIDD + h * DHEAD;
            kp[r][cc] = fmaxf(Km[base + cc], 0.f) + KEPS_F;
            vv[r][cc] = Vm[base + cc];
        }
        __syncthreads();
        for (int r = 0; r < 32; r++) {
#pragma unroll
            for (int i = 0; i < 5; i++) {
                if (i < 4 || has5) {
                    float vd = (od[i] < 32) ? vv[r][od[i]] : 1.0f;
                    acc[i] = fmaf(kp[r][om[i]], vd, acc[i]);
                }
            }
        }
        __syncthreads();
    }
    float* dst = KV + (size_t)bh * (32 * 33);
#pragma unroll
    for (int i = 0; i < 5; i++) {
        int o = tid + i * 256;
        if (o < 32 * 33) atomicAdd(&dst[o], acc[i]);
    }
}

// ---------------------------------------------------------------------------
// FAVOR num/den, in-place over Q: a[b,l,h,d] = (qp . KV[:,d]) / (qp . KV[:,32])
// ---------------------------------------------------------------------------
__global__ __launch_bounds__(256) void favor_kernel(
    float* __restrict__ Q, const float* __restrict__ KV)
{
    const int row = blockIdx.x;
    const int b = row >> 12;
    const int j = threadIdx.x;
    __shared__ float qp[HIDD];
    qp[j] = fmaxf(Q[(size_t)row * HIDD + j], 0.f) + KEPS_F;
    __syncthreads();
    const int h = j >> 5, d = j & 31;
    const float* kv = KV + ((size_t)(b * NHEAD + h)) * (32 * 33);
    float num = 0.f, den = 0.f;
#pragma unroll
    for (int m = 0; m < 32; m++) {
        float qm = qp[h * DHEAD + m];
        num = fmaf(qm, kv[m * 33 + d], num);
        den = fmaf(qm, kv[m * 33 + 32], den);
    }
    Q[(size_t)row * HIDD + j] = num / den;
}

// ---------------------------------------------------------------------------
// LayerNorm over 256 with prescale (fuses the o+o / h+h doubling)
// ---------------------------------------------------------------------------
__global__ __launch_bounds__(256) void ln_kernel(
    const float* __restrict__ in, const float* __restrict__ sc,
    const float* __restrict__ bi, float* __restrict__ out, float prescale)
{
    const size_t row = blockIdx.x;
    const int j = threadIdx.x;
    float v = in[row * HIDD + j] * prescale;
    float s = v, s2 = v * v;
#pragma unroll
    for (int off = 32; off > 0; off >>= 1) {
        s  += __shfl_down(s, off, 64);
        s2 += __shfl_down(s2, off, 64);
    }
    __shared__ float red[8];
    const int wid = j >> 6;
    if ((j & 63) == 0) { red[wid] = s; red[4 + wid] = s2; }
    __syncthreads();
    float ts  = red[0] + red[1] + red[2] + red[3];
    float ts2 = red[4] + red[5] + red[6] + red[7];
    float mean = ts * (1.0f / 256.0f);
    float var  = ts2 * (1.0f / 256.0f) - mean * mean;
    float rs = rsqrtf(var + LNEPS_F);
    out[row * HIDD + j] = (v - mean) * rs * sc[j] + bi[j];
}

// ---------------------------------------------------------------------------
// Head (fp32 out): out[0:4096] = x[:,0,:] ; out[4096:4608] = x[:,0,:]@qpW+qpb
// ---------------------------------------------------------------------------
__global__ __launch_bounds__(256) void head_kernel(
    const float* __restrict__ X, const float* __restrict__ qpW,
    const float* __restrict__ qpb, float* __restrict__ out)
{
    const int b = blockIdx.x, j = threadIdx.x;
    __shared__ float xr[HIDD];
    float v = X[((size_t)b * LSEQ) * HIDD + j];
    xr[j] = v;
    out[b * HIDD + j] = v;
    __syncthreads();
    if (j < 32) {
        float acc = qpb[j];
        for (int d = 0; d < HIDD; d++)
            acc = fmaf(xr[d], qpW[d * 32 + j], acc);
        out[NB * HIDD + b * 32 + j] = acc;
    }
}

// ---------------------------------------------------------------------------
extern "C" void kernel_launch(void* const* d_in, const int* in_sizes, int n_in,
                              void* d_out, int out_size, void* d_ws, size_t ws_size,
                              hipStream_t stream)
{
    const float* hidden = (const float*)d_in[0];
    const float* ins    = (const float*)d_in[1];
    const int*   resets = (const int*)d_in[2];
    const float* embW   = (const float*)d_in[3];
    const float* embb   = (const float*)d_in[4];
    const float* Wq = (const float*)d_in[5];
    const float* bq = (const float*)d_in[6];
    const float* Wk = (const float*)d_in[7];
    const float* bk = (const float*)d_in[8];
    const float* Wv = (const float*)d_in[9];
    const float* bv = (const float*)d_in[10];
    const float* Wo = (const float*)d_in[11];
    const float* bo = (const float*)d_in[12];
    const float* ln1s = (const float*)d_in[13];
    const float* ln1b = (const float*)d_in[14];
    const float* W1 = (const float*)d_in[15];
    const float* b1 = (const float*)d_in[16];
    const float* W2 = (const float*)d_in[17];
    const float* b2 = (const float*)d_in[18];
    const float* ln2s = (const float*)d_in[19];
    const float* ln2b = (const float*)d_in[20];
    const float* qpW = (const float*)d_in[21];
    const float* qpb = (const float*)d_in[22];

    // ---- workspace: exactly 4 x 64 MiB = 256 MiB, nothing beyond ----
    const size_t ACT_SZ = (size_t)MROWS * HIDD;       // 16.78M floats
    float* X  = (float*)d_ws;
    float* Qb = X  + ACT_SZ;
    float* Kb = Qb + ACT_SZ;
    float* Vb = Kb + ACT_SZ;
    float* KV = X;          // alias: X is dead between V-GEMM and LN1
    float* H1 = Qb;         // alias: Qb is dead after the Wo GEMM

    const dim3 blk(256);
    embed_kernel<<<MROWS, blk, 0, stream>>>(hidden, ins, resets, embW, embb, X);

    for (int l = 0; l < NLAY; l++) {
        const float* Wq_l = Wq + (size_t)l * HIDD * HIDD;
        const float* Wk_l = Wk + (size_t)l * HIDD * HIDD;
        const float* Wv_l = Wv + (size_t)l * HIDD * HIDD;
        const float* Wo_l = Wo + (size_t)l * HIDD * HIDD;
        const float* W1_l = W1 + (size_t)l * HIDD * FFD;
        const float* W2_l = W2 + (size_t)l * FFD * HIDD;

        gemm_f32<0><<<dim3(2, 512), blk, 0, stream>>>(X, Wq_l, bq + l * HIDD, Qb, MROWS, HIDD, HIDD);
        gemm_f32<0><<<dim3(2, 512), blk, 0, stream>>>(X, Wk_l, bk + l * HIDD, Kb, MROWS, HIDD, HIDD);
        gemm_f32<0><<<dim3(2, 512), blk, 0, stream>>>(X, Wv_l, bv + l * HIDD, Vb, MROWS, HIDD, HIDD);

        zero_kv<<<(KV_ELEMS + 255) / 256, blk, 0, stream>>>(KV);
        kv_kernel<<<dim3(NB * NHEAD, LSPLIT), blk, 0, stream>>>(Kb, Vb, KV);
        favor_kernel<<<MROWS, blk, 0, stream>>>(Qb, KV);

        gemm_f32<0><<<dim3(2, 512), blk, 0, stream>>>(Qb, Wo_l, bo + l * HIDD, Kb, MROWS, HIDD, HIDD);
        ln_kernel<<<MROWS, blk, 0, stream>>>(Kb, ln1s + l * HIDD, ln1b + l * HIDD, X, 2.0f);

        // FF in 8 chunks of 8192 rows; H1 (8192x1024 fp32 = 33.5 MB) fits in Qb
        for (int c = 0; c < 8; c++) {
            const size_t off = (size_t)c * 8192;
            gemm_f32<1><<<dim3(8, 64), blk, 0, stream>>>(X + off * HIDD, W1_l, b1 + l * FFD, H1, 8192, FFD, HIDD);
            gemm_f32<0><<<dim3(2, 64), blk, 0, stream>>>(H1, W2_l, b2 + l * HIDD, Vb + off * HIDD, 8192, HIDD, FFD);
        }
        ln_kernel<<<MROWS, blk, 0, stream>>>(Vb, ln2s + l * HIDD, ln2b + l * HIDD, X, 2.0f);
    }

    head_kernel<<<NB, blk, 0, stream>>>(X, qpW, qpb, (float*)d_out);
}

// Round 5
// 2379.386 us; speedup vs baseline: 4.2822x; 4.2822x over previous
//
#include <hip/hip_runtime.h>

// ---------------------------------------------------------------------------
// TransformerAgent (Performer/FAVOR+ encoder), MI355X gfx950.
// Round 5: bf16 MFMA GEMMs (m97 structure: 128x128 tile, BK=64,
// global_load_lds width 16, ds_read_b128 fragments, fp32 accumulate).
// Activations stored bf16; weights converted+transposed to bf16 [N][K]
// per launch. LN / FAVOR / epilogues in fp32. Output fp32.
// B=16, L=4096(=1+4095), HID=256, NH=8, DH=32, FF=1024, NL=4, ACT=32
// ---------------------------------------------------------------------------

typedef unsigned short bf16_t;
typedef __attribute__((ext_vector_type(8))) short short8;
typedef __attribute__((ext_vector_type(4))) float float4v;

#define NB 16
#define LSEQ 4096
#define MROWS (NB * LSEQ)      // 65536
#define HIDD 256
#define NHEAD 8
#define DHEAD 32
#define FFD 1024
#define NLAY 4
#define KEPS_F 1e-3f
#define LNEPS_F 1e-6f
#define KV_ELEMS (NB * NHEAD * 32 * 33)   // 135168

__device__ __forceinline__ float b2f(bf16_t h) {
    return __uint_as_float(((unsigned int)h) << 16);
}
__device__ __forceinline__ bf16_t f2b(float f) {
    unsigned int u = __float_as_uint(f);
    u += 0x7fffu + ((u >> 16) & 1u);   // round-to-nearest-even
    return (bf16_t)(u >> 16);
}

// async global->LDS, 16B per lane; per-lane gaddr = base + lane*16 pattern
#define GLOAD_LDS16(g, l)                                                     \
    __builtin_amdgcn_global_load_lds(                                         \
        (const __attribute__((address_space(1))) void*)(g),                   \
        (__attribute__((address_space(3))) void*)(l), 16, 0, 0)

// ---------------------------------------------------------------------------
// Convert+transpose: in[R][C] f32 (batch z) -> out[C][R] bf16. R,C % 32 == 0.
// ---------------------------------------------------------------------------
__global__ __launch_bounds__(256) void conv_transpose_kernel(
    const float* __restrict__ in, bf16_t* __restrict__ out, int R, int C)
{
    __shared__ float tile[32][33];
    const size_t ib = (size_t)blockIdx.z * R * C;
    const int r0 = blockIdx.y * 32, c0 = blockIdx.x * 32;
    const int tx = threadIdx.x & 31, ty = threadIdx.x >> 5;   // 32 x 8
#pragma unroll
    for (int rr = ty; rr < 32; rr += 8)
        tile[rr][tx] = in[ib + (size_t)(r0 + rr) * C + c0 + tx];
    __syncthreads();
#pragma unroll
    for (int rr = ty; rr < 32; rr += 8)
        out[ib + (size_t)(c0 + rr) * R + r0 + tx] = f2b(tile[tx][rr]);
}

// ---------------------------------------------------------------------------
// Embed A-prep: Ain[b*4096+l][128] = (l==0) ? 0 : bf16(ins[b][l-1][:])
// ---------------------------------------------------------------------------
__global__ __launch_bounds__(256) void prep_a_kernel(
    const float* __restrict__ ins, bf16_t* __restrict__ Ain)
{
    const int row = blockIdx.x * 2 + (threadIdx.x >> 7);
    const int j = threadIdx.x & 127;
    const int b = row >> 12, l = row & (LSEQ - 1);
    bf16_t v = 0;
    if (l != 0) v = f2b(ins[((size_t)b * 4095 + (l - 1)) * 128 + j]);
    Ain[(size_t)row * 128 + j] = v;
}

// X[b,0,:] = resets ? 0 : hidden (overwrites embed GEMM's bias-only row)
__global__ __launch_bounds__(256) void fix_row0_kernel(
    const float* __restrict__ hidden, const int* __restrict__ resets,
    bf16_t* __restrict__ X)
{
    const int b = blockIdx.x, j = threadIdx.x;
    float v = resets[b] ? 0.f : hidden[b * HIDD + j];
    X[((size_t)b * LSEQ) * HIDD + j] = f2b(v);
}

// ---------------------------------------------------------------------------
// MFMA GEMM: C[M,N] = act(A[M,K] @ W[K,N] + bias[N]); W given as WT[N][K].
// A, WT, C bf16; bias fp32; accumulate fp32. M%128==0, N%128==0, K%64==0.
// 256 thr = 4 waves; wave -> 64x64 via 4x4 grid of 16x16x32 MFMAs.
// MODE: 0 = none, 1 = relu.
// ---------------------------------------------------------------------------
template <int MODE>
__global__ __launch_bounds__(256) void gemm_mfma(
    const bf16_t* __restrict__ A, const bf16_t* __restrict__ WT,
    const float* __restrict__ bias, bf16_t* __restrict__ C,
    int M, int N, int K)
{
    __shared__ __align__(16) bf16_t As[128 * 64];   // [m][k]
    __shared__ __align__(16) bf16_t Bs[128 * 64];   // [n][k]
    const int tid = threadIdx.x;
    const int wave = tid >> 6, lane = tid & 63;
    const int bm = blockIdx.y * 128, bn = blockIdx.x * 128;
    const int quad = lane >> 4, mrow = lane & 15;
    const int wm0 = (wave & 1) * 64, wn0 = (wave >> 1) * 64;

    float4v acc[4][4];
#pragma unroll
    for (int i = 0; i < 4; i++)
#pragma unroll
        for (int j = 0; j < 4; j++) acc[i][j] = (float4v)(0.f);

    for (int k0 = 0; k0 < K; k0 += 64) {
#pragma unroll
        for (int is = 0; is < 4; is++) {
            const int c = (wave * 4 + is) * 64 + lane;   // 16B chunk idx 0..1023
            const int r = c >> 3, kofs = (c & 7) * 8;    // 8 chunks per 64-el row
            GLOAD_LDS16(A  + (size_t)(bm + r) * K + k0 + kofs, &As[c * 8]);
            GLOAD_LDS16(WT + (size_t)(bn + r) * K + k0 + kofs, &Bs[c * 8]);
        }
        __syncthreads();   // compiler emits vmcnt(0) drain before s_barrier
#pragma unroll
        for (int kc = 0; kc < 64; kc += 32) {
            short8 a[4], b[4];
#pragma unroll
            for (int i = 0; i < 4; i++)
                a[i] = *(const short8*)&As[(wm0 + i * 16 + mrow) * 64 + kc + quad * 8];
#pragma unroll
            for (int j = 0; j < 4; j++)
                b[j] = *(const short8*)&Bs[(wn0 + j * 16 + mrow) * 64 + kc + quad * 8];
#pragma unroll
            for (int i = 0; i < 4; i++)
#pragma unroll
                for (int j = 0; j < 4; j++)
                    acc[i][j] = __builtin_amdgcn_mfma_f32_16x16x32_bf16(
                        a[i], b[j], acc[i][j], 0, 0, 0);
        }
        __syncthreads();
    }

    // epilogue: C/D layout col=lane&15, row=quad*4+reg
    float bcol[4];
#pragma unroll
    for (int j = 0; j < 4; j++) bcol[j] = bias[bn + wn0 + j * 16 + mrow];
#pragma unroll
    for (int i = 0; i < 4; i++) {
#pragma unroll
        for (int r = 0; r < 4; r++) {
            const int grow = bm + wm0 + i * 16 + quad * 4 + r;
            bf16_t* crow = C + (size_t)grow * N + bn + wn0 + mrow;
#pragma unroll
            for (int j = 0; j < 4; j++) {
                float v = acc[i][j][r] + bcol[j];
                if (MODE == 1) v = fmaxf(v, 0.f);
                crow[j * 16] = f2b(v);
            }
        }
    }
}

// ---------------------------------------------------------------------------
// Zero the KV accumulator
// ---------------------------------------------------------------------------
__global__ __launch_bounds__(256) void zero_kv(float* __restrict__ KV)
{
    int i = blockIdx.x * 256 + threadIdx.x;
    if (i < KV_ELEMS) KV[i] = 0.f;
}

// ---------------------------------------------------------------------------
// FAVOR state: KV[b,h,m,d] = sum_l kp[b,l,h,m] * V_ext[b,l,h,d]
//   kp = relu(k)+eps ; V_ext = [v | 1]  (33 cols, col 32 = kp-sum)
// ---------------------------------------------------------------------------
#define LSPLIT 8
#define LCH (LSEQ / LSPLIT)    // 512

__global__ __launch_bounds__(256) void kv_kernel(
    const bf16_t* __restrict__ Km, const bf16_t* __restrict__ Vm,
    float* __restrict__ KV)
{
    const int bh = blockIdx.x;
    const int b = bh >> 3, h = bh & 7;
    const int l0 = blockIdx.y * LCH;
    const int tid = threadIdx.x;
    __shared__ float kp[32][33];
    __shared__ float vv[32][33];

    float acc[5] = {0.f, 0.f, 0.f, 0.f, 0.f};
    int om[5], od[5];
#pragma unroll
    for (int i = 0; i < 5; i++) {
        int o = tid + i * 256;
        om[i] = (o < 32 * 33) ? (o / 33) : 0;
        od[i] = (o < 32 * 33) ? (o % 33) : 0;
    }
    const bool has5 = (tid < (33 * 32 - 1024));

    for (int c = 0; c < LCH; c += 32) {
        for (int e = tid; e < 1024; e += 256) {
            int r = e >> 5, cc = e & 31;
            size_t base = ((size_t)(b * LSEQ + l0 + c + r)) * HIDD + h * DHEAD;
            kp[r][cc] = fmaxf(b2f(Km[base + cc]), 0.f) + KEPS_F;
            vv[r][cc] = b2f(Vm[base + cc]);
        }
        __syncthreads();
        for (int r = 0; r < 32; r++) {
#pragma unroll
            for (int i = 0; i < 5; i++) {
                if (i < 4 || has5) {
                    float vd = (od[i] < 32) ? vv[r][od[i]] : 1.0f;
                    acc[i] = fmaf(kp[r][om[i]], vd, acc[i]);
                }
            }
        }
        __syncthreads();
    }
    float* dst = KV + (size_t)bh * (32 * 33);
#pragma unroll
    for (int i = 0; i < 5; i++) {
        int o = tid + i * 256;
        if (o < 32 * 33) atomicAdd(&dst[o], acc[i]);
    }
}

// ---------------------------------------------------------------------------
// FAVOR num/den, in-place over Q (bf16)
// ---------------------------------------------------------------------------
__global__ __launch_bounds__(256) void favor_kernel(
    bf16_t* __restrict__ Q, const float* __restrict__ KV)
{
    const int row = blockIdx.x;
    const int b = row >> 12;
    const int j = threadIdx.x;
    __shared__ float qp[HIDD];
    qp[j] = fmaxf(b2f(Q[(size_t)row * HIDD + j]), 0.f) + KEPS_F;
    __syncthreads();
    const int h = j >> 5, d = j & 31;
    const float* kv = KV + ((size_t)(b * NHEAD + h)) * (32 * 33);
    float num = 0.f, den = 0.f;
#pragma unroll
    for (int m = 0; m < 32; m++) {
        float qm = qp[h * DHEAD + m];
        num = fmaf(qm, kv[m * 33 + d], num);
        den = fmaf(qm, kv[m * 33 + 32], den);
    }
    Q[(size_t)row * HIDD + j] = f2b(num / den);
}

// ---------------------------------------------------------------------------
// LayerNorm over 256 (bf16 in/out, fp32 stats); prescale fuses o+o
// ---------------------------------------------------------------------------
__global__ __launch_bounds__(256) void ln_kernel(
    const bf16_t* __restrict__ in, const float* __restrict__ sc,
    const float* __restrict__ bi, bf16_t* __restrict__ out, float prescale)
{
    const size_t row = blockIdx.x;
    const int j = threadIdx.x;
    float v = b2f(in[row * HIDD + j]) * prescale;
    float s = v, s2 = v * v;
#pragma unroll
    for (int off = 32; off > 0; off >>= 1) {
        s  += __shfl_down(s, off, 64);
        s2 += __shfl_down(s2, off, 64);
    }
    __shared__ float red[8];
    const int wid = j >> 6;
    if ((j & 63) == 0) { red[wid] = s; red[4 + wid] = s2; }
    __syncthreads();
    float ts  = red[0] + red[1] + red[2] + red[3];
    float ts2 = red[4] + red[5] + red[6] + red[7];
    float mean = ts * (1.0f / 256.0f);
    float var  = ts2 * (1.0f / 256.0f) - mean * mean;
    float rs = rsqrtf(var + LNEPS_F);
    out[row * HIDD + j] = f2b((v - mean) * rs * sc[j] + bi[j]);
}

// ---------------------------------------------------------------------------
// Head (fp32 out): out[0:4096] = x[:,0,:] ; out[4096:4608] = x@qpW + qpb
// ---------------------------------------------------------------------------
__global__ __launch_bounds__(256) void head_kernel(
    const bf16_t* __restrict__ X, const float* __restrict__ qpW,
    const float* __restrict__ qpb, float* __restrict__ out)
{
    const int b = blockIdx.x, j = threadIdx.x;
    __shared__ float xr[HIDD];
    float v = b2f(X[((size_t)b * LSEQ) * HIDD + j]);
    xr[j] = v;
    out[b * HIDD + j] = v;
    __syncthreads();
    if (j < 32) {
        float acc = qpb[j];
        for (int d = 0; d < HIDD; d++)
            acc = fmaf(xr[d], qpW[d * 32 + j], acc);
        out[NB * HIDD + b * 32 + j] = acc;
    }
}

// ---------------------------------------------------------------------------
extern "C" void kernel_launch(void* const* d_in, const int* in_sizes, int n_in,
                              void* d_out, int out_size, void* d_ws, size_t ws_size,
                              hipStream_t stream)
{
    const float* hidden = (const float*)d_in[0];
    const float* ins    = (const float*)d_in[1];
    const int*   resets = (const int*)d_in[2];
    const float* embW   = (const float*)d_in[3];
    const float* embb   = (const float*)d_in[4];
    const float* Wq = (const float*)d_in[5];
    const float* bq = (const float*)d_in[6];
    const float* Wk = (const float*)d_in[7];
    const float* bk = (const float*)d_in[8];
    const float* Wv = (const float*)d_in[9];
    const float* bv = (const float*)d_in[10];
    const float* Wo = (const float*)d_in[11];
    const float* bo = (const float*)d_in[12];
    const float* ln1s = (const float*)d_in[13];
    const float* ln1b = (const float*)d_in[14];
    const float* W1 = (const float*)d_in[15];
    const float* b1 = (const float*)d_in[16];
    const float* W2 = (const float*)d_in[17];
    const float* b2 = (const float*)d_in[18];
    const float* ln2s = (const float*)d_in[19];
    const float* ln2b = (const float*)d_in[20];
    const float* qpW = (const float*)d_in[21];
    const float* qpb = (const float*)d_in[22];

    // ---- workspace layout (bf16 activations), ~208 MB < 256 MiB ----
    const size_t ACT_SZ = (size_t)MROWS * HIDD;            // 16.78M elems
    char* base = (char*)d_ws;
    bf16_t* X  = (bf16_t*)base;                            // 33.5 MB
    bf16_t* Qb = X  + ACT_SZ;
    bf16_t* Kb = Qb + ACT_SZ;
    bf16_t* Vb = Kb + ACT_SZ;
    bf16_t* H1 = Vb + ACT_SZ;                              // 32768x1024 = 67 MB
    bf16_t* Ain = H1;                                      // alias (pre-layer only)
    float*  KV = (float*)(H1 + (size_t)32768 * FFD);       // 0.54 MB
    bf16_t* WqT = (bf16_t*)(KV + KV_ELEMS);                // transposed weights
    bf16_t* WkT = WqT + (size_t)NLAY * HIDD * HIDD;
    bf16_t* WvT = WkT + (size_t)NLAY * HIDD * HIDD;
    bf16_t* WoT = WvT + (size_t)NLAY * HIDD * HIDD;
    bf16_t* W1T = WoT + (size_t)NLAY * HIDD * HIDD;
    bf16_t* W2T = W1T + (size_t)NLAY * HIDD * FFD;
    bf16_t* embWT = W2T + (size_t)NLAY * FFD * HIDD;

    const dim3 blk(256);

    // ---- weight conversion (f32 [K][N] -> bf16 [N][K]) ----
    conv_transpose_kernel<<<dim3(8, 8, NLAY), blk, 0, stream>>>(Wq, WqT, HIDD, HIDD);
    conv_transpose_kernel<<<dim3(8, 8, NLAY), blk, 0, stream>>>(Wk, WkT, HIDD, HIDD);
    conv_transpose_kernel<<<dim3(8, 8, NLAY), blk, 0, stream>>>(Wv, WvT, HIDD, HIDD);
    conv_transpose_kernel<<<dim3(8, 8, NLAY), blk, 0, stream>>>(Wo, WoT, HIDD, HIDD);
    conv_transpose_kernel<<<dim3(32, 8, NLAY), blk, 0, stream>>>(W1, W1T, HIDD, FFD);
    conv_transpose_kernel<<<dim3(8, 32, NLAY), blk, 0, stream>>>(W2, W2T, FFD, HIDD);
    conv_transpose_kernel<<<dim3(8, 4, 1), blk, 0, stream>>>(embW, embWT, 128, HIDD);

    // ---- embed: Ain = [0 | bf16(ins)], X = Ain @ embW + embb, fix row 0 ----
    prep_a_kernel<<<MROWS / 2, blk, 0, stream>>>(ins, Ain);
    gemm_mfma<0><<<dim3(2, 512), blk, 0, stream>>>(Ain, embWT, embb, X, MROWS, HIDD, 128);
    fix_row0_kernel<<<NB, blk, 0, stream>>>(hidden, resets, X);

    for (int l = 0; l < NLAY; l++) {
        const size_t wofs = (size_t)l * HIDD * HIDD;
        gemm_mfma<0><<<dim3(2, 512), blk, 0, stream>>>(X, WqT + wofs, bq + l * HIDD, Qb, MROWS, HIDD, HIDD);
        gemm_mfma<0><<<dim3(2, 512), blk, 0, stream>>>(X, WkT + wofs, bk + l * HIDD, Kb, MROWS, HIDD, HIDD);
        gemm_mfma<0><<<dim3(2, 512), blk, 0, stream>>>(X, WvT + wofs, bv + l * HIDD, Vb, MROWS, HIDD, HIDD);

        zero_kv<<<(KV_ELEMS + 255) / 256, blk, 0, stream>>>(KV);
        kv_kernel<<<dim3(NB * NHEAD, LSPLIT), blk, 0, stream>>>(Kb, Vb, KV);
        favor_kernel<<<MROWS, blk, 0, stream>>>(Qb, KV);

        gemm_mfma<0><<<dim3(2, 512), blk, 0, stream>>>(Qb, WoT + wofs, bo + l * HIDD, Kb, MROWS, HIDD, HIDD);
        ln_kernel<<<MROWS, blk, 0, stream>>>(Kb, ln1s + l * HIDD, ln1b + l * HIDD, X, 2.0f);

        // FF in 2 chunks of 32768 rows (H1 = 67 MB bf16)
        for (int c = 0; c < 2; c++) {
            const size_t off = (size_t)c * 32768;
            gemm_mfma<1><<<dim3(8, 256), blk, 0, stream>>>(X + off * HIDD, W1T + (size_t)l * HIDD * FFD,
                                                           b1 + l * FFD, H1, 32768, FFD, HIDD);
            gemm_mfma<0><<<dim3(2, 256), blk, 0, stream>>>(H1, W2T + (size_t)l * FFD * HIDD,
                                                           b2 + l * HIDD, Vb + off * HIDD, 32768, HIDD, FFD);
        }
        ln_kernel<<<MROWS, blk, 0, stream>>>(Vb, ln2s + l * HIDD, ln2b + l * HIDD, X, 2.0f);
    }

    head_kernel<<<NB, blk, 0, stream>>>(X, qpW, qpb, (float*)d_out);
}

// Round 6
// 1776.864 us; speedup vs baseline: 5.7342x; 1.3391x over previous
//
#include <hip/hip_runtime.h>

// ---------------------------------------------------------------------------
// TransformerAgent (Performer/FAVOR+ encoder), MI355X gfx950.
// Round 6: favor as MFMA GEMM (per-head [Lx32]@[32x33], K=32 = one
// 16x16x32 step; A-frag straight from global, B-frag from LDS kvT);
// LN as one-row-per-wave shfl_xor butterfly. GEMMs unchanged (m97-style).
// B=16, L=4096(=1+4095), HID=256, NH=8, DH=32, FF=1024, NL=4, ACT=32
// ---------------------------------------------------------------------------

typedef unsigned short bf16_t;
typedef __attribute__((ext_vector_type(8))) short short8;
typedef __attribute__((ext_vector_type(4))) float float4v;

#define NB 16
#define LSEQ 4096
#define MROWS (NB * LSEQ)      // 65536
#define HIDD 256
#define NHEAD 8
#define DHEAD 32
#define FFD 1024
#define NLAY 4
#define KEPS_F 1e-3f
#define LNEPS_F 1e-6f
#define KV_ELEMS (NB * NHEAD * 32 * 33)   // 135168

__device__ __forceinline__ float b2f(bf16_t h) {
    return __uint_as_float(((unsigned int)h) << 16);
}
__device__ __forceinline__ bf16_t f2b(float f) {
    unsigned int u = __float_as_uint(f);
    u += 0x7fffu + ((u >> 16) & 1u);   // round-to-nearest-even
    return (bf16_t)(u >> 16);
}

// async global->LDS, 16B per lane
#define GLOAD_LDS16(g, l)                                                     \
    __builtin_amdgcn_global_load_lds(                                         \
        (const __attribute__((address_space(1))) void*)(g),                   \
        (__attribute__((address_space(3))) void*)(l), 16, 0, 0)

// ---------------------------------------------------------------------------
// Convert+transpose: in[R][C] f32 (batch z) -> out[C][R] bf16. R,C % 32 == 0.
// ---------------------------------------------------------------------------
__global__ __launch_bounds__(256) void conv_transpose_kernel(
    const float* __restrict__ in, bf16_t* __restrict__ out, int R, int C)
{
    __shared__ float tile[32][33];
    const size_t ib = (size_t)blockIdx.z * R * C;
    const int r0 = blockIdx.y * 32, c0 = blockIdx.x * 32;
    const int tx = threadIdx.x & 31, ty = threadIdx.x >> 5;   // 32 x 8
#pragma unroll
    for (int rr = ty; rr < 32; rr += 8)
        tile[rr][tx] = in[ib + (size_t)(r0 + rr) * C + c0 + tx];
    __syncthreads();
#pragma unroll
    for (int rr = ty; rr < 32; rr += 8)
        out[ib + (size_t)(c0 + rr) * R + r0 + tx] = f2b(tile[tx][rr]);
}

// ---------------------------------------------------------------------------
// Embed A-prep: Ain[b*4096+l][128] = (l==0) ? 0 : bf16(ins[b][l-1][:])
// ---------------------------------------------------------------------------
__global__ __launch_bounds__(256) void prep_a_kernel(
    const float* __restrict__ ins, bf16_t* __restrict__ Ain)
{
    const int row = blockIdx.x * 2 + (threadIdx.x >> 7);
    const int j = threadIdx.x & 127;
    const int b = row >> 12, l = row & (LSEQ - 1);
    bf16_t v = 0;
    if (l != 0) v = f2b(ins[((size_t)b * 4095 + (l - 1)) * 128 + j]);
    Ain[(size_t)row * 128 + j] = v;
}

// X[b,0,:] = resets ? 0 : hidden (overwrites embed GEMM's bias-only row)
__global__ __launch_bounds__(256) void fix_row0_kernel(
    const float* __restrict__ hidden, const int* __restrict__ resets,
    bf16_t* __restrict__ X)
{
    const int b = blockIdx.x, j = threadIdx.x;
    float v = resets[b] ? 0.f : hidden[b * HIDD + j];
    X[((size_t)b * LSEQ) * HIDD + j] = f2b(v);
}

// ---------------------------------------------------------------------------
// MFMA GEMM: C[M,N] = act(A[M,K] @ W[K,N] + bias[N]); W given as WT[N][K].
// 256 thr = 4 waves; wave -> 64x64 via 4x4 grid of 16x16x32 MFMAs.
// ---------------------------------------------------------------------------
template <int MODE>
__global__ __launch_bounds__(256) void gemm_mfma(
    const bf16_t* __restrict__ A, const bf16_t* __restrict__ WT,
    const float* __restrict__ bias, bf16_t* __restrict__ C,
    int M, int N, int K)
{
    __shared__ __align__(16) bf16_t As[128 * 64];   // [m][k]
    __shared__ __align__(16) bf16_t Bs[128 * 64];   // [n][k]
    const int tid = threadIdx.x;
    const int wave = tid >> 6, lane = tid & 63;
    const int bm = blockIdx.y * 128, bn = blockIdx.x * 128;
    const int quad = lane >> 4, mrow = lane & 15;
    const int wm0 = (wave & 1) * 64, wn0 = (wave >> 1) * 64;

    float4v acc[4][4];
#pragma unroll
    for (int i = 0; i < 4; i++)
#pragma unroll
        for (int j = 0; j < 4; j++) acc[i][j] = (float4v)(0.f);

    for (int k0 = 0; k0 < K; k0 += 64) {
#pragma unroll
        for (int is = 0; is < 4; is++) {
            const int c = (wave * 4 + is) * 64 + lane;   // 16B chunk idx 0..1023
            const int r = c >> 3, kofs = (c & 7) * 8;
            GLOAD_LDS16(A  + (size_t)(bm + r) * K + k0 + kofs, &As[c * 8]);
            GLOAD_LDS16(WT + (size_t)(bn + r) * K + k0 + kofs, &Bs[c * 8]);
        }
        __syncthreads();
#pragma unroll
        for (int kc = 0; kc < 64; kc += 32) {
            short8 a[4], b[4];
#pragma unroll
            for (int i = 0; i < 4; i++)
                a[i] = *(const short8*)&As[(wm0 + i * 16 + mrow) * 64 + kc + quad * 8];
#pragma unroll
            for (int j = 0; j < 4; j++)
                b[j] = *(const short8*)&Bs[(wn0 + j * 16 + mrow) * 64 + kc + quad * 8];
#pragma unroll
            for (int i = 0; i < 4; i++)
#pragma unroll
                for (int j = 0; j < 4; j++)
                    acc[i][j] = __builtin_amdgcn_mfma_f32_16x16x32_bf16(
                        a[i], b[j], acc[i][j], 0, 0, 0);
        }
        __syncthreads();
    }

    float bcol[4];
#pragma unroll
    for (int j = 0; j < 4; j++) bcol[j] = bias[bn + wn0 + j * 16 + mrow];
#pragma unroll
    for (int i = 0; i < 4; i++) {
#pragma unroll
        for (int r = 0; r < 4; r++) {
            const int grow = bm + wm0 + i * 16 + quad * 4 + r;
            bf16_t* crow = C + (size_t)grow * N + bn + wn0 + mrow;
#pragma unroll
            for (int j = 0; j < 4; j++) {
                float v = acc[i][j][r] + bcol[j];
                if (MODE == 1) v = fmaxf(v, 0.f);
                crow[j * 16] = f2b(v);
            }
        }
    }
}

// ---------------------------------------------------------------------------
// Zero the KV accumulator
// ---------------------------------------------------------------------------
__global__ __launch_bounds__(256) void zero_kv(float* __restrict__ KV)
{
    int i = blockIdx.x * 256 + threadIdx.x;
    if (i < KV_ELEMS) KV[i] = 0.f;
}

// ---------------------------------------------------------------------------
// FAVOR state: KV[b,h,m,d] = sum_l kp[b,l,h,m] * V_ext[b,l,h,d]
//   kp = relu(k)+eps ; V_ext = [v | 1]  (33 cols, col 32 = kp-sum)
// ---------------------------------------------------------------------------
#define LSPLIT 8
#define LCH (LSEQ / LSPLIT)    // 512

__global__ __launch_bounds__(256) void kv_kernel(
    const bf16_t* __restrict__ Km, const bf16_t* __restrict__ Vm,
    float* __restrict__ KV)
{
    const int bh = blockIdx.x;
    const int b = bh >> 3, h = bh & 7;
    const int l0 = blockIdx.y * LCH;
    const int tid = threadIdx.x;
    __shared__ float kp[32][33];
    __shared__ float vv[32][33];

    float acc[5] = {0.f, 0.f, 0.f, 0.f, 0.f};
    int om[5], od[5];
#pragma unroll
    for (int i = 0; i < 5; i++) {
        int o = tid + i * 256;
        om[i] = (o < 32 * 33) ? (o / 33) : 0;
        od[i] = (o < 32 * 33) ? (o % 33) : 0;
    }
    const bool has5 = (tid < (33 * 32 - 1024));

    for (int c = 0; c < LCH; c += 32) {
        for (int e = tid; e < 1024; e += 256) {
            int r = e >> 5, cc = e & 31;
            size_t base = ((size_t)(b * LSEQ + l0 + c + r)) * HIDD + h * DHEAD;
            kp[r][cc] = fmaxf(b2f(Km[base + cc]), 0.f) + KEPS_F;
            vv[r][cc] = b2f(Vm[base + cc]);
        }
        __syncthreads();
        for (int r = 0; r < 32; r++) {
#pragma unroll
            for (int i = 0; i < 5; i++) {
                if (i < 4 || has5) {
                    float vd = (od[i] < 32) ? vv[r][od[i]] : 1.0f;
                    acc[i] = fmaf(kp[r][om[i]], vd, acc[i]);
                }
            }
        }
        __syncthreads();
    }
    float* dst = KV + (size_t)bh * (32 * 33);
#pragma unroll
    for (int i = 0; i < 5; i++) {
        int o = tid + i * 256;
        if (o < 32 * 33) atomicAdd(&dst[o], acc[i]);
    }
}

// ---------------------------------------------------------------------------
// FAVOR num/den via MFMA, in-place over Q.
// Per (b,h): [num|den] = qp[L x 32] @ kv_ext[32 x 33]  (K=32: ONE 16x16x32
// MFMA k-step). A-frag loaded straight from global Q (cols h*32+quad*8,
// 16B contiguous). B-frag from LDS kvT[h][d(pad 48)][m] (same layout as the
// working gemm_mfma B-path). den = padded column 32, shfl-broadcast.
// In-place is safe: per h, reads/writes touch disjoint column sets except
// the current h, where the wave's MFMA read precedes its own writes.
// Block: 256 thr = 4 waves, 128 rows (32/wave); grid = B * 32.
// ---------------------------------------------------------------------------
__global__ __launch_bounds__(256) void favor_mfma(
    bf16_t* __restrict__ Q, const float* __restrict__ KV)
{
    __shared__ __align__(16) bf16_t kvT[NHEAD * 48 * 32];   // 24 KB
    const int blk = blockIdx.x;
    const int b = blk >> 5;
    const int row0 = b * LSEQ + (blk & 31) * 128;
    const int tid = threadIdx.x;

    // build kvT[h][d][m] = bf16(KV[b,h,m,d]) ; d in [33,48) -> 0
    for (int e = tid; e < NHEAD * 48 * 32; e += 256) {
        const int h = e / (48 * 32);
        const int rem = e - h * (48 * 32);
        const int d = rem >> 5, m = rem & 31;
        bf16_t v = 0;
        if (d < 33) v = f2b(KV[((size_t)(b * NHEAD + h)) * (32 * 33) + m * 33 + d]);
        kvT[e] = v;
    }
    __syncthreads();

    const int wave = tid >> 6, lane = tid & 63;
    const int quad = lane >> 4, mr = lane & 15;
    const int wrow0 = row0 + wave * 32;

    for (int h = 0; h < NHEAD; h++) {
        short8 bf[3];
#pragma unroll
        for (int t = 0; t < 3; t++)
            bf[t] = *(const short8*)&kvT[(h * 48 + t * 16 + mr) * 32 + quad * 8];
#pragma unroll
        for (int mt = 0; mt < 2; mt++) {
            const int r0 = wrow0 + mt * 16;
            // A fragment: qp = relu(q)+eps for row r0+mr, cols h*32+quad*8..+7
            short8 araw = *(const short8*)(Q + (size_t)(r0 + mr) * HIDD + h * 32 + quad * 8);
            short8 a;
#pragma unroll
            for (int j = 0; j < 8; j++)
                a[j] = (short)f2b(fmaxf(b2f((bf16_t)araw[j]), 0.f) + KEPS_F);
            float4v c0 = __builtin_amdgcn_mfma_f32_16x16x32_bf16(a, bf[0], (float4v)(0.f), 0, 0, 0);
            float4v c1 = __builtin_amdgcn_mfma_f32_16x16x32_bf16(a, bf[1], (float4v)(0.f), 0, 0, 0);
            float4v c2 = __builtin_amdgcn_mfma_f32_16x16x32_bf16(a, bf[2], (float4v)(0.f), 0, 0, 0);
#pragma unroll
            for (int r = 0; r < 4; r++) {
                const float den = __shfl(c2[r], quad << 4);   // C[row][32] from lane quad*16
                const float rinv = 1.0f / den;
                bf16_t* qrow = Q + (size_t)(r0 + quad * 4 + r) * HIDD + h * 32;
                qrow[mr]      = f2b(c0[r] * rinv);
                qrow[16 + mr] = f2b(c1[r] * rinv);
            }
        }
    }
}

// ---------------------------------------------------------------------------
// LayerNorm: one row per WAVE (64 lanes x 4 elems), shfl_xor butterfly,
// no LDS, no syncthreads. prescale fuses the o+o / h+h doubling.
// ---------------------------------------------------------------------------
__global__ __launch_bounds__(256) void ln_kernel(
    const bf16_t* __restrict__ in, const float* __restrict__ sc,
    const float* __restrict__ bi, bf16_t* __restrict__ out, float prescale)
{
    const int wave = threadIdx.x >> 6, lane = threadIdx.x & 63;
    const size_t row = (size_t)blockIdx.x * 4 + wave;
    const int c = lane * 4;
    ushort4 raw = *(const ushort4*)(in + row * HIDD + c);
    float v0 = b2f(raw.x) * prescale, v1 = b2f(raw.y) * prescale;
    float v2 = b2f(raw.z) * prescale, v3 = b2f(raw.w) * prescale;
    float s  = v0 + v1 + v2 + v3;
    float s2 = v0 * v0 + v1 * v1 + v2 * v2 + v3 * v3;
#pragma unroll
    for (int off = 1; off < 64; off <<= 1) {
        s  += __shfl_xor(s, off, 64);
        s2 += __shfl_xor(s2, off, 64);
    }
    const float mean = s * (1.0f / 256.0f);
    const float var  = s2 * (1.0f / 256.0f) - mean * mean;
    const float rs = rsqrtf(var + LNEPS_F);
    const float4 scv = *(const float4*)(sc + c);
    const float4 biv = *(const float4*)(bi + c);
    ushort4 o;
    o.x = f2b((v0 - mean) * rs * scv.x + biv.x);
    o.y = f2b((v1 - mean) * rs * scv.y + biv.y);
    o.z = f2b((v2 - mean) * rs * scv.z + biv.z);
    o.w = f2b((v3 - mean) * rs * scv.w + biv.w);
    *(ushort4*)(out + row * HIDD + c) = o;
}

// ---------------------------------------------------------------------------
// Head (fp32 out): out[0:4096] = x[:,0,:] ; out[4096:4608] = x@qpW + qpb
// ---------------------------------------------------------------------------
__global__ __launch_bounds__(256) void head_kernel(
    const bf16_t* __restrict__ X, const float* __restrict__ qpW,
    const float* __restrict__ qpb, float* __restrict__ out)
{
    const int b = blockIdx.x, j = threadIdx.x;
    __shared__ float xr[HIDD];
    float v = b2f(X[((size_t)b * LSEQ) * HIDD + j]);
    xr[j] = v;
    out[b * HIDD + j] = v;
    __syncthreads();
    if (j < 32) {
        float acc = qpb[j];
        for (int d = 0; d < HIDD; d++)
            acc = fmaf(xr[d], qpW[d * 32 + j], acc);
        out[NB * HIDD + b * 32 + j] = acc;
    }
}

// ---------------------------------------------------------------------------
extern "C" void kernel_launch(void* const* d_in, const int* in_sizes, int n_in,
                              void* d_out, int out_size, void* d_ws, size_t ws_size,
                              hipStream_t stream)
{
    const float* hidden = (const float*)d_in[0];
    const float* ins    = (const float*)d_in[1];
    const int*   resets = (const int*)d_in[2];
    const float* embW   = (const float*)d_in[3];
    const float* embb   = (const float*)d_in[4];
    const float* Wq = (const float*)d_in[5];
    const float* bq = (const float*)d_in[6];
    const float* Wk = (const float*)d_in[7];
    const float* bk = (const float*)d_in[8];
    const float* Wv = (const float*)d_in[9];
    const float* bv = (const float*)d_in[10];
    const float* Wo = (const float*)d_in[11];
    const float* bo = (const float*)d_in[12];
    const float* ln1s = (const float*)d_in[13];
    const float* ln1b = (const float*)d_in[14];
    const float* W1 = (const float*)d_in[15];
    const float* b1 = (const float*)d_in[16];
    const float* W2 = (const float*)d_in[17];
    const float* b2 = (const float*)d_in[18];
    const float* ln2s = (const float*)d_in[19];
    const float* ln2b = (const float*)d_in[20];
    const float* qpW = (const float*)d_in[21];
    const float* qpb = (const float*)d_in[22];

    // ---- workspace layout (bf16 activations), ~208 MB < 256 MiB ----
    const size_t ACT_SZ = (size_t)MROWS * HIDD;            // 16.78M elems
    char* base = (char*)d_ws;
    bf16_t* X  = (bf16_t*)base;                            // 33.5 MB
    bf16_t* Qb = X  + ACT_SZ;
    bf16_t* Kb = Qb + ACT_SZ;
    bf16_t* Vb = Kb + ACT_SZ;
    bf16_t* H1 = Vb + ACT_SZ;                              // 32768x1024 = 67 MB
    bf16_t* Ain = H1;                                      // alias (pre-layer only)
    float*  KV = (float*)(H1 + (size_t)32768 * FFD);       // 0.54 MB
    bf16_t* WqT = (bf16_t*)(KV + KV_ELEMS);
    bf16_t* WkT = WqT + (size_t)NLAY * HIDD * HIDD;
    bf16_t* WvT = WkT + (size_t)NLAY * HIDD * HIDD;
    bf16_t* WoT = WvT + (size_t)NLAY * HIDD * HIDD;
    bf16_t* W1T = WoT + (size_t)NLAY * HIDD * HIDD;
    bf16_t* W2T = W1T + (size_t)NLAY * HIDD * FFD;
    bf16_t* embWT = W2T + (size_t)NLAY * FFD * HIDD;

    const dim3 blk(256);

    conv_transpose_kernel<<<dim3(8, 8, NLAY), blk, 0, stream>>>(Wq, WqT, HIDD, HIDD);
    conv_transpose_kernel<<<dim3(8, 8, NLAY), blk, 0, stream>>>(Wk, WkT, HIDD, HIDD);
    conv_transpose_kernel<<<dim3(8, 8, NLAY), blk, 0, stream>>>(Wv, WvT, HIDD, HIDD);
    conv_transpose_kernel<<<dim3(8, 8, NLAY), blk, 0, stream>>>(Wo, WoT, HIDD, HIDD);
    conv_transpose_kernel<<<dim3(32, 8, NLAY), blk, 0, stream>>>(W1, W1T, HIDD, FFD);
    conv_transpose_kernel<<<dim3(8, 32, NLAY), blk, 0, stream>>>(W2, W2T, FFD, HIDD);
    conv_transpose_kernel<<<dim3(8, 4, 1), blk, 0, stream>>>(embW, embWT, 128, HIDD);

    prep_a_kernel<<<MROWS / 2, blk, 0, stream>>>(ins, Ain);
    gemm_mfma<0><<<dim3(2, 512), blk, 0, stream>>>(Ain, embWT, embb, X, MROWS, HIDD, 128);
    fix_row0_kernel<<<NB, blk, 0, stream>>>(hidden, resets, X);

    for (int l = 0; l < NLAY; l++) {
        const size_t wofs = (size_t)l * HIDD * HIDD;
        gemm_mfma<0><<<dim3(2, 512), blk, 0, stream>>>(X, WqT + wofs, bq + l * HIDD, Qb, MROWS, HIDD, HIDD);
        gemm_mfma<0><<<dim3(2, 512), blk, 0, stream>>>(X, WkT + wofs, bk + l * HIDD, Kb, MROWS, HIDD, HIDD);
        gemm_mfma<0><<<dim3(2, 512), blk, 0, stream>>>(X, WvT + wofs, bv + l * HIDD, Vb, MROWS, HIDD, HIDD);

        zero_kv<<<(KV_ELEMS + 255) / 256, blk, 0, stream>>>(KV);
        kv_kernel<<<dim3(NB * NHEAD, LSPLIT), blk, 0, stream>>>(Kb, Vb, KV);
        favor_mfma<<<NB * 32, blk, 0, stream>>>(Qb, KV);

        gemm_mfma<0><<<dim3(2, 512), blk, 0, stream>>>(Qb, WoT + wofs, bo + l * HIDD, Kb, MROWS, HIDD, HIDD);
        ln_kernel<<<MROWS / 4, blk, 0, stream>>>(Kb, ln1s + l * HIDD, ln1b + l * HIDD, X, 2.0f);

        for (int c = 0; c < 2; c++) {
            const size_t off = (size_t)c * 32768;
            gemm_mfma<1><<<dim3(8, 256), blk, 0, stream>>>(X + off * HIDD, W1T + (size_t)l * HIDD * FFD,
                                                           b1 + l * FFD, H1, 32768, FFD, HIDD);
            gemm_mfma<0><<<dim3(2, 256), blk, 0, stream>>>(H1, W2T + (size_t)l * FFD * HIDD,
                                                           b2 + l * HIDD, Vb + off * HIDD, 32768, HIDD, FFD);
        }
        ln_kernel<<<MROWS / 4, blk, 0, stream>>>(Vb, ln2s + l * HIDD, ln2b + l * HIDD, X, 2.0f);
    }

    head_kernel<<<NB, blk, 0, stream>>>(X, qpW, qpb, (float*)d_out);
}

// Round 7
// 1402.712 us; speedup vs baseline: 7.2638x; 1.2667x over previous
//
#include <hip/hip_runtime.h>

// ---------------------------------------------------------------------------
// TransformerAgent (Performer/FAVOR+ encoder), MI355X gfx950.
// Round 7: kv-state as MFMA GEMM (kp^T @ [V|1] per (b,h), LDS-transposed
// fragments); QKV fused into one GEMM (WqkvT [768][256] -> QKV [M][768],
// gemm gains lda/ldc). favor/LN unchanged from round 6.
// B=16, L=4096(=1+4095), HID=256, NH=8, DH=32, FF=1024, NL=4, ACT=32
// ---------------------------------------------------------------------------

typedef unsigned short bf16_t;
typedef __attribute__((ext_vector_type(8))) short short8;
typedef __attribute__((ext_vector_type(4))) float float4v;

#define NB 16
#define LSEQ 4096
#define MROWS (NB * LSEQ)      // 65536
#define HIDD 256
#define NHEAD 8
#define DHEAD 32
#define FFD 1024
#define NLAY 4
#define KEPS_F 1e-3f
#define LNEPS_F 1e-6f
#define KV_ELEMS (NB * NHEAD * 32 * 33)   // 135168

__device__ __forceinline__ float b2f(bf16_t h) {
    return __uint_as_float(((unsigned int)h) << 16);
}
__device__ __forceinline__ bf16_t f2b(float f) {
    unsigned int u = __float_as_uint(f);
    u += 0x7fffu + ((u >> 16) & 1u);   // round-to-nearest-even
    return (bf16_t)(u >> 16);
}

// async global->LDS, 16B per lane
#define GLOAD_LDS16(g, l)                                                     \
    __builtin_amdgcn_global_load_lds(                                         \
        (const __attribute__((address_space(1))) void*)(g),                   \
        (__attribute__((address_space(3))) void*)(l), 16, 0, 0)

// ---------------------------------------------------------------------------
// Convert+transpose: in[z*ils + R][C] f32 -> out[z*ols + C][R] bf16.
// ---------------------------------------------------------------------------
__global__ __launch_bounds__(256) void conv_transpose_kernel(
    const float* __restrict__ in, bf16_t* __restrict__ out, int R, int C,
    size_t ils, size_t ols)
{
    __shared__ float tile[32][33];
    const size_t ib = (size_t)blockIdx.z * ils;
    const size_t ob = (size_t)blockIdx.z * ols;
    const int r0 = blockIdx.y * 32, c0 = blockIdx.x * 32;
    const int tx = threadIdx.x & 31, ty = threadIdx.x >> 5;   // 32 x 8
#pragma unroll
    for (int rr = ty; rr < 32; rr += 8)
        tile[rr][tx] = in[ib + (size_t)(r0 + rr) * C + c0 + tx];
    __syncthreads();
#pragma unroll
    for (int rr = ty; rr < 32; rr += 8)
        out[ob + (size_t)(c0 + rr) * R + r0 + tx] = f2b(tile[tx][rr]);
}

// concat per-layer q/k/v biases into bqkv[l][768]
__global__ __launch_bounds__(256) void concat_bias_kernel(
    const float* __restrict__ bq, const float* __restrict__ bk,
    const float* __restrict__ bv, float* __restrict__ bqkv)
{
    const int l = blockIdx.x, j = threadIdx.x;
    bqkv[l * 768 + j]       = bq[l * 256 + j];
    bqkv[l * 768 + 256 + j] = bk[l * 256 + j];
    bqkv[l * 768 + 512 + j] = bv[l * 256 + j];
}

// ---------------------------------------------------------------------------
// Embed A-prep: Ain[b*4096+l][128] = (l==0) ? 0 : bf16(ins[b][l-1][:])
// ---------------------------------------------------------------------------
__global__ __launch_bounds__(256) void prep_a_kernel(
    const float* __restrict__ ins, bf16_t* __restrict__ Ain)
{
    const int row = blockIdx.x * 2 + (threadIdx.x >> 7);
    const int j = threadIdx.x & 127;
    const int b = row >> 12, l = row & (LSEQ - 1);
    bf16_t v = 0;
    if (l != 0) v = f2b(ins[((size_t)b * 4095 + (l - 1)) * 128 + j]);
    Ain[(size_t)row * 128 + j] = v;
}

// X[b,0,:] = resets ? 0 : hidden
__global__ __launch_bounds__(256) void fix_row0_kernel(
    const float* __restrict__ hidden, const int* __restrict__ resets,
    bf16_t* __restrict__ X)
{
    const int b = blockIdx.x, j = threadIdx.x;
    float v = resets[b] ? 0.f : hidden[b * HIDD + j];
    X[((size_t)b * LSEQ) * HIDD + j] = f2b(v);
}

// ---------------------------------------------------------------------------
// MFMA GEMM: C[M,N] = act(A[M,K] @ W[K,N] + bias[N]); W given as WT[N][K].
// A row stride lda, C row stride ldc. 256 thr = 4 waves, 128x128 tile.
// ---------------------------------------------------------------------------
template <int MODE>
__global__ __launch_bounds__(256) void gemm_mfma(
    const bf16_t* __restrict__ A, const bf16_t* __restrict__ WT,
    const float* __restrict__ bias, bf16_t* __restrict__ C,
    int M, int N, int K, int lda, int ldc)
{
    __shared__ __align__(16) bf16_t As[128 * 64];   // [m][k]
    __shared__ __align__(16) bf16_t Bs[128 * 64];   // [n][k]
    const int tid = threadIdx.x;
    const int wave = tid >> 6, lane = tid & 63;
    const int bm = blockIdx.y * 128, bn = blockIdx.x * 128;
    const int quad = lane >> 4, mrow = lane & 15;
    const int wm0 = (wave & 1) * 64, wn0 = (wave >> 1) * 64;

    float4v acc[4][4];
#pragma unroll
    for (int i = 0; i < 4; i++)
#pragma unroll
        for (int j = 0; j < 4; j++) acc[i][j] = (float4v)(0.f);

    for (int k0 = 0; k0 < K; k0 += 64) {
#pragma unroll
        for (int is = 0; is < 4; is++) {
            const int c = (wave * 4 + is) * 64 + lane;   // 16B chunk idx 0..1023
            const int r = c >> 3, kofs = (c & 7) * 8;
            GLOAD_LDS16(A  + (size_t)(bm + r) * lda + k0 + kofs, &As[c * 8]);
            GLOAD_LDS16(WT + (size_t)(bn + r) * K   + k0 + kofs, &Bs[c * 8]);
        }
        __syncthreads();
#pragma unroll
        for (int kc = 0; kc < 64; kc += 32) {
            short8 a[4], b[4];
#pragma unroll
            for (int i = 0; i < 4; i++)
                a[i] = *(const short8*)&As[(wm0 + i * 16 + mrow) * 64 + kc + quad * 8];
#pragma unroll
            for (int j = 0; j < 4; j++)
                b[j] = *(const short8*)&Bs[(wn0 + j * 16 + mrow) * 64 + kc + quad * 8];
#pragma unroll
            for (int i = 0; i < 4; i++)
#pragma unroll
                for (int j = 0; j < 4; j++)
                    acc[i][j] = __builtin_amdgcn_mfma_f32_16x16x32_bf16(
                        a[i], b[j], acc[i][j], 0, 0, 0);
        }
        __syncthreads();
    }

    float bcol[4];
#pragma unroll
    for (int j = 0; j < 4; j++) bcol[j] = bias[bn + wn0 + j * 16 + mrow];
#pragma unroll
    for (int i = 0; i < 4; i++) {
#pragma unroll
        for (int r = 0; r < 4; r++) {
            const int grow = bm + wm0 + i * 16 + quad * 4 + r;
            bf16_t* crow = C + (size_t)grow * ldc + bn + wn0 + mrow;
#pragma unroll
            for (int j = 0; j < 4; j++) {
                float v = acc[i][j][r] + bcol[j];
                if (MODE == 1) v = fmaxf(v, 0.f);
                crow[j * 16] = f2b(v);
            }
        }
    }
}

// ---------------------------------------------------------------------------
// Zero the KV accumulator
// ---------------------------------------------------------------------------
__global__ __launch_bounds__(256) void zero_kv(float* __restrict__ KV)
{
    int i = blockIdx.x * 256 + threadIdx.x;
    if (i < KV_ELEMS) KV[i] = 0.f;
}

// ---------------------------------------------------------------------------
// FAVOR kv state via MFMA. Per (b,h): KV[32x33] = kp^T[32xL] @ [V|1][Lx33].
// kp = relu(K)+eps. Block = (bh, 512-l split); 4 staging passes of 128 l
// into LDS raw tiles; MFMA frags read transposed via strided ds_read_u16.
// Per-wave fp32 acc (2 m-tiles x 3 d-tiles), LDS cross-wave reduce, atomics.
// K/V live in fused QKV buffer: row stride 768, K at col 256, V at 512.
// ---------------------------------------------------------------------------
__global__ __launch_bounds__(256) void kv_mfma(
    const bf16_t* __restrict__ QKV, float* __restrict__ KV)
{
    __shared__ __align__(16) char smem[24576];
    bf16_t (*kp)[36] = (bf16_t(*)[36])smem;                 // 128x36x2 = 9216 B
    bf16_t (*vv)[52] = (bf16_t(*)[52])(smem + 9216);        // 128x52x2 = 13312 B
    float (*red)[6][64][4] = (float(*)[6][64][4])smem;      // 24576 B (aliases)

    const int bh = blockIdx.x;
    const int b = bh >> 3, h = bh & 7;
    const size_t rowbase = (size_t)b * LSEQ + blockIdx.y * 512;
    const int tid = threadIdx.x;
    const int wave = tid >> 6, lane = tid & 63;
    const int quad = lane >> 4, mr = lane & 15;

    // init vv cols 32..51 once: col 32 = 1.0 (den column), rest 0
    for (int e = tid; e < 128 * 20; e += 256) {
        const int l = e / 20, c = 32 + (e % 20);
        vv[l][c] = (c == 32) ? (bf16_t)0x3F80 : (bf16_t)0;
    }

    float4v acc[2][3];
#pragma unroll
    for (int i = 0; i < 2; i++)
#pragma unroll
        for (int t = 0; t < 3; t++) acc[i][t] = (float4v)(0.f);

    for (int pass = 0; pass < 4; pass++) {
        __syncthreads();   // prev-pass frag reads (and init) complete
        const size_t lp = rowbase + pass * 128;
#pragma unroll
        for (int it = 0; it < 4; it++) {
            const int e = tid + it * 256;          // 0..1023
            const int l = e >> 3, c0 = (e & 7) * 4;
            const bf16_t* src = QKV + (lp + l) * 768 + 256 + h * 32 + c0;
            ushort4 kq = *(const ushort4*)src;
            ushort4 vq = *(const ushort4*)(src + 256);
            ushort4 ko;
            ko.x = f2b(fmaxf(b2f(kq.x), 0.f) + KEPS_F);
            ko.y = f2b(fmaxf(b2f(kq.y), 0.f) + KEPS_F);
            ko.z = f2b(fmaxf(b2f(kq.z), 0.f) + KEPS_F);
            ko.w = f2b(fmaxf(b2f(kq.w), 0.f) + KEPS_F);
            *(ushort4*)&kp[l][c0] = ko;
            *(ushort4*)&vv[l][c0] = vq;
        }
        __syncthreads();

        // wave's 32-l k-step: frags via strided LDS reads (transpose)
        const int lw = wave * 32 + quad * 8;
        short8 a[2], bb[3];
#pragma unroll
        for (int i = 0; i < 2; i++)
#pragma unroll
            for (int j = 0; j < 8; j++)
                a[i][j] = (short)kp[lw + j][i * 16 + mr];
#pragma unroll
        for (int t = 0; t < 3; t++)
#pragma unroll
            for (int j = 0; j < 8; j++)
                bb[t][j] = (short)vv[lw + j][t * 16 + mr];
#pragma unroll
        for (int i = 0; i < 2; i++)
#pragma unroll
            for (int t = 0; t < 3; t++)
                acc[i][t] = __builtin_amdgcn_mfma_f32_16x16x32_bf16(
                    a[i], bb[t], acc[i][t], 0, 0, 0);
    }

    __syncthreads();
#pragma unroll
    for (int i = 0; i < 2; i++)
#pragma unroll
        for (int t = 0; t < 3; t++)
#pragma unroll
            for (int r = 0; r < 4; r++)
                red[wave][i * 3 + t][lane][r] = acc[i][t][r];
    __syncthreads();

    float* dst = KV + (size_t)bh * (32 * 33);
    for (int e = tid; e < 6 * 64 * 4; e += 256) {
        const int t = e >> 8, li = (e >> 2) & 63, r = e & 3;
        const float s = red[0][t][li][r] + red[1][t][li][r]
                      + red[2][t][li][r] + red[3][t][li][r];
        const int i = t / 3, j = t % 3;
        const int m = i * 16 + (li >> 4) * 4 + r;
        const int d = j * 16 + (li & 15);
        if (d < 33) atomicAdd(&dst[m * 33 + d], s);
    }
}

// ---------------------------------------------------------------------------
// FAVOR num/den via MFMA, in-place over Q region of fused QKV (stride 768).
// ---------------------------------------------------------------------------
__global__ __launch_bounds__(256) void favor_mfma(
    bf16_t* __restrict__ QKV, const float* __restrict__ KV)
{
    __shared__ __align__(16) bf16_t kvT[NHEAD * 48 * 32];   // 24 KB
    const int blk = blockIdx.x;
    const int b = blk >> 5;
    const int row0 = b * LSEQ + (blk & 31) * 128;
    const int tid = threadIdx.x;

    for (int e = tid; e < NHEAD * 48 * 32; e += 256) {
        const int h = e / (48 * 32);
        const int rem = e - h * (48 * 32);
        const int d = rem >> 5, m = rem & 31;
        bf16_t v = 0;
        if (d < 33) v = f2b(KV[((size_t)(b * NHEAD + h)) * (32 * 33) + m * 33 + d]);
        kvT[e] = v;
    }
    __syncthreads();

    const int wave = tid >> 6, lane = tid & 63;
    const int quad = lane >> 4, mr = lane & 15;
    const int wrow0 = row0 + wave * 32;

    for (int h = 0; h < NHEAD; h++) {
        short8 bf[3];
#pragma unroll
        for (int t = 0; t < 3; t++)
            bf[t] = *(const short8*)&kvT[(h * 48 + t * 16 + mr) * 32 + quad * 8];
#pragma unroll
        for (int mt = 0; mt < 2; mt++) {
            const int r0 = wrow0 + mt * 16;
            short8 araw = *(const short8*)(QKV + (size_t)(r0 + mr) * 768 + h * 32 + quad * 8);
            short8 a;
#pragma unroll
            for (int j = 0; j < 8; j++)
                a[j] = (short)f2b(fmaxf(b2f((bf16_t)araw[j]), 0.f) + KEPS_F);
            float4v c0 = __builtin_amdgcn_mfma_f32_16x16x32_bf16(a, bf[0], (float4v)(0.f), 0, 0, 0);
            float4v c1 = __builtin_amdgcn_mfma_f32_16x16x32_bf16(a, bf[1], (float4v)(0.f), 0, 0, 0);
            float4v c2 = __builtin_amdgcn_mfma_f32_16x16x32_bf16(a, bf[2], (float4v)(0.f), 0, 0, 0);
#pragma unroll
            for (int r = 0; r < 4; r++) {
                const float den = __shfl(c2[r], quad << 4);
                const float rinv = 1.0f / den;
                bf16_t* qrow = QKV + (size_t)(r0 + quad * 4 + r) * 768 + h * 32;
                qrow[mr]      = f2b(c0[r] * rinv);
                qrow[16 + mr] = f2b(c1[r] * rinv);
            }
        }
    }
}

// ---------------------------------------------------------------------------
// LayerNorm: one row per WAVE, shfl_xor butterfly; prescale fuses doubling.
// ---------------------------------------------------------------------------
__global__ __launch_bounds__(256) void ln_kernel(
    const bf16_t* __restrict__ in, const float* __restrict__ sc,
    const float* __restrict__ bi, bf16_t* __restrict__ out, float prescale)
{
    const int wave = threadIdx.x >> 6, lane = threadIdx.x & 63;
    const size_t row = (size_t)blockIdx.x * 4 + wave;
    const int c = lane * 4;
    ushort4 raw = *(const ushort4*)(in + row * HIDD + c);
    float v0 = b2f(raw.x) * prescale, v1 = b2f(raw.y) * prescale;
    float v2 = b2f(raw.z) * prescale, v3 = b2f(raw.w) * prescale;
    float s  = v0 + v1 + v2 + v3;
    float s2 = v0 * v0 + v1 * v1 + v2 * v2 + v3 * v3;
#pragma unroll
    for (int off = 1; off < 64; off <<= 1) {
        s  += __shfl_xor(s, off, 64);
        s2 += __shfl_xor(s2, off, 64);
    }
    const float mean = s * (1.0f / 256.0f);
    const float var  = s2 * (1.0f / 256.0f) - mean * mean;
    const float rs = rsqrtf(var + LNEPS_F);
    const float4 scv = *(const float4*)(sc + c);
    const float4 biv = *(const float4*)(bi + c);
    ushort4 o;
    o.x = f2b((v0 - mean) * rs * scv.x + biv.x);
    o.y = f2b((v1 - mean) * rs * scv.y + biv.y);
    o.z = f2b((v2 - mean) * rs * scv.z + biv.z);
    o.w = f2b((v3 - mean) * rs * scv.w + biv.w);
    *(ushort4*)(out + row * HIDD + c) = o;
}

// ---------------------------------------------------------------------------
// Head (fp32 out): out[0:4096] = x[:,0,:] ; out[4096:4608] = x@qpW + qpb
// ---------------------------------------------------------------------------
__global__ __launch_bounds__(256) void head_kernel(
    const bf16_t* __restrict__ X, const float* __restrict__ qpW,
    const float* __restrict__ qpb, float* __restrict__ out)
{
    const int b = blockIdx.x, j = threadIdx.x;
    __shared__ float xr[HIDD];
    float v = b2f(X[((size_t)b * LSEQ) * HIDD + j]);
    xr[j] = v;
    out[b * HIDD + j] = v;
    __syncthreads();
    if (j < 32) {
        float acc = qpb[j];
        for (int d = 0; d < HIDD; d++)
            acc = fmaf(xr[d], qpW[d * 32 + j], acc);
        out[NB * HIDD + b * 32 + j] = acc;
    }
}

// ---------------------------------------------------------------------------
extern "C" void kernel_launch(void* const* d_in, const int* in_sizes, int n_in,
                              void* d_out, int out_size, void* d_ws, size_t ws_size,
                              hipStream_t stream)
{
    const float* hidden = (const float*)d_in[0];
    const float* ins    = (const float*)d_in[1];
    const int*   resets = (const int*)d_in[2];
    const float* embW   = (const float*)d_in[3];
    const float* embb   = (const float*)d_in[4];
    const float* Wq = (const float*)d_in[5];
    const float* bq = (const float*)d_in[6];
    const float* Wk = (const float*)d_in[7];
    const float* bk = (const float*)d_in[8];
    const float* Wv = (const float*)d_in[9];
    const float* bv = (const float*)d_in[10];
    const float* Wo = (const float*)d_in[11];
    const float* bo = (const float*)d_in[12];
    const float* ln1s = (const float*)d_in[13];
    const float* ln1b = (const float*)d_in[14];
    const float* W1 = (const float*)d_in[15];
    const float* b1 = (const float*)d_in[16];
    const float* W2 = (const float*)d_in[17];
    const float* b2 = (const float*)d_in[18];
    const float* ln2s = (const float*)d_in[19];
    const float* ln2b = (const float*)d_in[20];
    const float* qpW = (const float*)d_in[21];
    const float* qpb = (const float*)d_in[22];

    // ---- workspace (~243 MB < 256 MiB) ----
    const size_t ACT_SZ = (size_t)MROWS * HIDD;            // 16.78M elems
    bf16_t* X    = (bf16_t*)d_ws;                          // 33.5 MB
    bf16_t* QKV  = X + ACT_SZ;                             // 65536x768 = 100.7 MB
    bf16_t* T    = QKV + (size_t)MROWS * 768;              // 33.5 MB (Wo/FF2 out)
    bf16_t* H1   = T + ACT_SZ;                             // 32768x1024 = 67 MB
    bf16_t* Ain  = H1;                                     // alias (pre-layer)
    float*  KV   = (float*)(H1 + (size_t)32768 * FFD);     // 0.54 MB
    float*  bqkv = KV + KV_ELEMS;                          // 4x768 f32
    bf16_t* WqkvT = (bf16_t*)(bqkv + NLAY * 768);          // [l][768][256]
    bf16_t* WoT   = WqkvT + (size_t)NLAY * 3 * HIDD * HIDD;
    bf16_t* W1T   = WoT + (size_t)NLAY * HIDD * HIDD;
    bf16_t* W2T   = W1T + (size_t)NLAY * HIDD * FFD;
    bf16_t* embWT = W2T + (size_t)NLAY * FFD * HIDD;

    const dim3 blk(256);
    const size_t HH = (size_t)HIDD * HIDD;

    conv_transpose_kernel<<<dim3(8, 8, NLAY), blk, 0, stream>>>(Wq, WqkvT,          HIDD, HIDD, HH, 3 * HH);
    conv_transpose_kernel<<<dim3(8, 8, NLAY), blk, 0, stream>>>(Wk, WqkvT + HH,     HIDD, HIDD, HH, 3 * HH);
    conv_transpose_kernel<<<dim3(8, 8, NLAY), blk, 0, stream>>>(Wv, WqkvT + 2 * HH, HIDD, HIDD, HH, 3 * HH);
    conv_transpose_kernel<<<dim3(8, 8, NLAY), blk, 0, stream>>>(Wo, WoT, HIDD, HIDD, HH, HH);
    conv_transpose_kernel<<<dim3(32, 8, NLAY), blk, 0, stream>>>(W1, W1T, HIDD, FFD, (size_t)HIDD * FFD, (size_t)HIDD * FFD);
    conv_transpose_kernel<<<dim3(8, 32, NLAY), blk, 0, stream>>>(W2, W2T, FFD, HIDD, (size_t)HIDD * FFD, (size_t)HIDD * FFD);
    conv_transpose_kernel<<<dim3(8, 4, 1), blk, 0, stream>>>(embW, embWT, 128, HIDD, 0, 0);
    concat_bias_kernel<<<NLAY, blk, 0, stream>>>(bq, bk, bv, bqkv);

    prep_a_kernel<<<MROWS / 2, blk, 0, stream>>>(ins, Ain);
    gemm_mfma<0><<<dim3(2, 512), blk, 0, stream>>>(Ain, embWT, embb, X, MROWS, HIDD, 128, 128, HIDD);
    fix_row0_kernel<<<NB, blk, 0, stream>>>(hidden, resets, X);

    for (int l = 0; l < NLAY; l++) {
        // fused QKV projection: X[M][256] @ Wqkv[256][768] -> QKV[M][768]
        gemm_mfma<0><<<dim3(6, 512), blk, 0, stream>>>(X, WqkvT + (size_t)l * 3 * HH,
                                                       bqkv + l * 768, QKV, MROWS, 768, HIDD, HIDD, 768);

        zero_kv<<<(KV_ELEMS + 255) / 256, blk, 0, stream>>>(KV);
        kv_mfma<<<dim3(NB * NHEAD, 8), blk, 0, stream>>>(QKV, KV);
        favor_mfma<<<NB * 32, blk, 0, stream>>>(QKV, KV);

        gemm_mfma<0><<<dim3(2, 512), blk, 0, stream>>>(QKV, WoT + (size_t)l * HH,
                                                       bo + l * HIDD, T, MROWS, HIDD, HIDD, 768, HIDD);
        ln_kernel<<<MROWS / 4, blk, 0, stream>>>(T, ln1s + l * HIDD, ln1b + l * HIDD, X, 2.0f);

        for (int c = 0; c < 2; c++) {
            const size_t off = (size_t)c * 32768;
            gemm_mfma<1><<<dim3(8, 256), blk, 0, stream>>>(X + off * HIDD, W1T + (size_t)l * HIDD * FFD,
                                                           b1 + l * FFD, H1, 32768, FFD, HIDD, HIDD, FFD);
            gemm_mfma<0><<<dim3(2, 256), blk, 0, stream>>>(H1, W2T + (size_t)l * FFD * HIDD,
                                                           b2 + l * HIDD, T + off * HIDD, 32768, HIDD, FFD, FFD, HIDD);
        }
        ln_kernel<<<MROWS / 4, blk, 0, stream>>>(T, ln2s + l * HIDD, ln2b + l * HIDD, X, 2.0f);
    }

    head_kernel<<<NB, blk, 0, stream>>>(X, qpW, qpb, (float*)d_out);
}

// Round 8
// 1346.430 us; speedup vs baseline: 7.5674x; 1.0418x over previous
//
#include <hip/hip_runtime.h>

// ---------------------------------------------------------------------------
// TransformerAgent (Performer/FAVOR+ encoder), MI355X gfx950.
// Round 8: XOR-swizzled LDS layout in gemm_mfma (kills the 16-way bank
// conflict on ds_read_b128 fragment reads: logical chunk j of row r lives at
// physical chunk j^(r&7); staging fetches the matching global chunk since
// global_load_lds' LDS dest is lane-linear). favor kvT m-stride padded 32->40.
// B=16, L=4096(=1+4095), HID=256, NH=8, DH=32, FF=1024, NL=4, ACT=32
// ---------------------------------------------------------------------------

typedef unsigned short bf16_t;
typedef __attribute__((ext_vector_type(8))) short short8;
typedef __attribute__((ext_vector_type(4))) float float4v;

#define NB 16
#define LSEQ 4096
#define MROWS (NB * LSEQ)      // 65536
#define HIDD 256
#define NHEAD 8
#define DHEAD 32
#define FFD 1024
#define NLAY 4
#define KEPS_F 1e-3f
#define LNEPS_F 1e-6f
#define KV_ELEMS (NB * NHEAD * 32 * 33)   // 135168

__device__ __forceinline__ float b2f(bf16_t h) {
    return __uint_as_float(((unsigned int)h) << 16);
}
__device__ __forceinline__ bf16_t f2b(float f) {
    unsigned int u = __float_as_uint(f);
    u += 0x7fffu + ((u >> 16) & 1u);   // round-to-nearest-even
    return (bf16_t)(u >> 16);
}

// async global->LDS, 16B per lane
#define GLOAD_LDS16(g, l)                                                     \
    __builtin_amdgcn_global_load_lds(                                         \
        (const __attribute__((address_space(1))) void*)(g),                   \
        (__attribute__((address_space(3))) void*)(l), 16, 0, 0)

// ---------------------------------------------------------------------------
// Convert+transpose: in[z*ils + R][C] f32 -> out[z*ols + C][R] bf16.
// ---------------------------------------------------------------------------
__global__ __launch_bounds__(256) void conv_transpose_kernel(
    const float* __restrict__ in, bf16_t* __restrict__ out, int R, int C,
    size_t ils, size_t ols)
{
    __shared__ float tile[32][33];
    const size_t ib = (size_t)blockIdx.z * ils;
    const size_t ob = (size_t)blockIdx.z * ols;
    const int r0 = blockIdx.y * 32, c0 = blockIdx.x * 32;
    const int tx = threadIdx.x & 31, ty = threadIdx.x >> 5;   // 32 x 8
#pragma unroll
    for (int rr = ty; rr < 32; rr += 8)
        tile[rr][tx] = in[ib + (size_t)(r0 + rr) * C + c0 + tx];
    __syncthreads();
#pragma unroll
    for (int rr = ty; rr < 32; rr += 8)
        out[ob + (size_t)(c0 + rr) * R + r0 + tx] = f2b(tile[tx][rr]);
}

// concat per-layer q/k/v biases into bqkv[l][768]
__global__ __launch_bounds__(256) void concat_bias_kernel(
    const float* __restrict__ bq, const float* __restrict__ bk,
    const float* __restrict__ bv, float* __restrict__ bqkv)
{
    const int l = blockIdx.x, j = threadIdx.x;
    bqkv[l * 768 + j]       = bq[l * 256 + j];
    bqkv[l * 768 + 256 + j] = bk[l * 256 + j];
    bqkv[l * 768 + 512 + j] = bv[l * 256 + j];
}

// ---------------------------------------------------------------------------
// Embed A-prep: Ain[b*4096+l][128] = (l==0) ? 0 : bf16(ins[b][l-1][:])
// ---------------------------------------------------------------------------
__global__ __launch_bounds__(256) void prep_a_kernel(
    const float* __restrict__ ins, bf16_t* __restrict__ Ain)
{
    const int row = blockIdx.x * 2 + (threadIdx.x >> 7);
    const int j = threadIdx.x & 127;
    const int b = row >> 12, l = row & (LSEQ - 1);
    bf16_t v = 0;
    if (l != 0) v = f2b(ins[((size_t)b * 4095 + (l - 1)) * 128 + j]);
    Ain[(size_t)row * 128 + j] = v;
}

// X[b,0,:] = resets ? 0 : hidden
__global__ __launch_bounds__(256) void fix_row0_kernel(
    const float* __restrict__ hidden, const int* __restrict__ resets,
    bf16_t* __restrict__ X)
{
    const int b = blockIdx.x, j = threadIdx.x;
    float v = resets[b] ? 0.f : hidden[b * HIDD + j];
    X[((size_t)b * LSEQ) * HIDD + j] = f2b(v);
}

// ---------------------------------------------------------------------------
// MFMA GEMM: C[M,N] = act(A[M,K] @ W[K,N] + bias[N]); W given as WT[N][K].
// A row stride lda, C row stride ldc. 256 thr = 4 waves, 128x128 tile.
// LDS rows are 8 chunks of 16B; logical chunk j stored at j^(r&7).
// ---------------------------------------------------------------------------
template <int MODE>
__global__ __launch_bounds__(256) void gemm_mfma(
    const bf16_t* __restrict__ A, const bf16_t* __restrict__ WT,
    const float* __restrict__ bias, bf16_t* __restrict__ C,
    int M, int N, int K, int lda, int ldc)
{
    __shared__ __align__(16) bf16_t As[128 * 64];   // [m][k], swizzled
    __shared__ __align__(16) bf16_t Bs[128 * 64];   // [n][k], swizzled
    const int tid = threadIdx.x;
    const int wave = tid >> 6, lane = tid & 63;
    const int bm = blockIdx.y * 128, bn = blockIdx.x * 128;
    const int quad = lane >> 4, mrow = lane & 15;
    const int mxor = mrow & 7;
    const int wm0 = (wave & 1) * 64, wn0 = (wave >> 1) * 64;

    float4v acc[4][4];
#pragma unroll
    for (int i = 0; i < 4; i++)
#pragma unroll
        for (int j = 0; j < 4; j++) acc[i][j] = (float4v)(0.f);

    for (int k0 = 0; k0 < K; k0 += 64) {
#pragma unroll
        for (int is = 0; is < 4; is++) {
            const int c = (wave * 4 + is) * 64 + lane;   // physical chunk 0..1023
            const int r = c >> 3;
            const int kofs = ((c & 7) ^ (r & 7)) * 8;    // logical chunk for this slot
            GLOAD_LDS16(A  + (size_t)(bm + r) * lda + k0 + kofs, &As[c * 8]);
            GLOAD_LDS16(WT + (size_t)(bn + r) * K   + k0 + kofs, &Bs[c * 8]);
        }
        __syncthreads();
#pragma unroll
        for (int kk = 0; kk < 8; kk += 4) {              // kc = kk*8 (0,32)
            short8 a[4], b[4];
#pragma unroll
            for (int i = 0; i < 4; i++) {
                const int row = wm0 + i * 16 + mrow;
                a[i] = *(const short8*)&As[(row * 8 + ((quad + kk) ^ mxor)) * 8];
            }
#pragma unroll
            for (int j = 0; j < 4; j++) {
                const int row = wn0 + j * 16 + mrow;
                b[j] = *(const short8*)&Bs[(row * 8 + ((quad + kk) ^ mxor)) * 8];
            }
#pragma unroll
            for (int i = 0; i < 4; i++)
#pragma unroll
                for (int j = 0; j < 4; j++)
                    acc[i][j] = __builtin_amdgcn_mfma_f32_16x16x32_bf16(
                        a[i], b[j], acc[i][j], 0, 0, 0);
        }
        __syncthreads();
    }

    float bcol[4];
#pragma unroll
    for (int j = 0; j < 4; j++) bcol[j] = bias[bn + wn0 + j * 16 + mrow];
#pragma unroll
    for (int i = 0; i < 4; i++) {
#pragma unroll
        for (int r = 0; r < 4; r++) {
            const int grow = bm + wm0 + i * 16 + quad * 4 + r;
            bf16_t* crow = C + (size_t)grow * ldc + bn + wn0 + mrow;
#pragma unroll
            for (int j = 0; j < 4; j++) {
                float v = acc[i][j][r] + bcol[j];
                if (MODE == 1) v = fmaxf(v, 0.f);
                crow[j * 16] = f2b(v);
            }
        }
    }
}

// ---------------------------------------------------------------------------
// Zero the KV accumulator
// ---------------------------------------------------------------------------
__global__ __launch_bounds__(256) void zero_kv(float* __restrict__ KV)
{
    int i = blockIdx.x * 256 + threadIdx.x;
    if (i < KV_ELEMS) KV[i] = 0.f;
}

// ---------------------------------------------------------------------------
// FAVOR kv state via MFMA. Per (b,h): KV[32x33] = kp^T[32xL] @ [V|1][Lx33].
// ---------------------------------------------------------------------------
__global__ __launch_bounds__(256) void kv_mfma(
    const bf16_t* __restrict__ QKV, float* __restrict__ KV)
{
    __shared__ __align__(16) char smem[24576];
    bf16_t (*kp)[36] = (bf16_t(*)[36])smem;                 // 128x36x2 = 9216 B
    bf16_t (*vv)[52] = (bf16_t(*)[52])(smem + 9216);        // 128x52x2 = 13312 B
    float (*red)[6][64][4] = (float(*)[6][64][4])smem;      // 24576 B (aliases)

    const int bh = blockIdx.x;
    const int b = bh >> 3, h = bh & 7;
    const size_t rowbase = (size_t)b * LSEQ + blockIdx.y * 512;
    const int tid = threadIdx.x;
    const int wave = tid >> 6, lane = tid & 63;
    const int quad = lane >> 4, mr = lane & 15;

    // init vv cols 32..51 once: col 32 = 1.0 (den column), rest 0
    for (int e = tid; e < 128 * 20; e += 256) {
        const int l = e / 20, c = 32 + (e % 20);
        vv[l][c] = (c == 32) ? (bf16_t)0x3F80 : (bf16_t)0;
    }

    float4v acc[2][3];
#pragma unroll
    for (int i = 0; i < 2; i++)
#pragma unroll
        for (int t = 0; t < 3; t++) acc[i][t] = (float4v)(0.f);

    for (int pass = 0; pass < 4; pass++) {
        __syncthreads();
        const size_t lp = rowbase + pass * 128;
#pragma unroll
        for (int it = 0; it < 4; it++) {
            const int e = tid + it * 256;          // 0..1023
            const int l = e >> 3, c0 = (e & 7) * 4;
            const bf16_t* src = QKV + (lp + l) * 768 + 256 + h * 32 + c0;
            ushort4 kq = *(const ushort4*)src;
            ushort4 vq = *(const ushort4*)(src + 256);
            ushort4 ko;
            ko.x = f2b(fmaxf(b2f(kq.x), 0.f) + KEPS_F);
            ko.y = f2b(fmaxf(b2f(kq.y), 0.f) + KEPS_F);
            ko.z = f2b(fmaxf(b2f(kq.z), 0.f) + KEPS_F);
            ko.w = f2b(fmaxf(b2f(kq.w), 0.f) + KEPS_F);
            *(ushort4*)&kp[l][c0] = ko;
            *(ushort4*)&vv[l][c0] = vq;
        }
        __syncthreads();

        const int lw = wave * 32 + quad * 8;
        short8 a[2], bb[3];
#pragma unroll
        for (int i = 0; i < 2; i++)
#pragma unroll
            for (int j = 0; j < 8; j++)
                a[i][j] = (short)kp[lw + j][i * 16 + mr];
#pragma unroll
        for (int t = 0; t < 3; t++)
#pragma unroll
            for (int j = 0; j < 8; j++)
                bb[t][j] = (short)vv[lw + j][t * 16 + mr];
#pragma unroll
        for (int i = 0; i < 2; i++)
#pragma unroll
            for (int t = 0; t < 3; t++)
                acc[i][t] = __builtin_amdgcn_mfma_f32_16x16x32_bf16(
                    a[i], bb[t], acc[i][t], 0, 0, 0);
    }

    __syncthreads();
#pragma unroll
    for (int i = 0; i < 2; i++)
#pragma unroll
        for (int t = 0; t < 3; t++)
#pragma unroll
            for (int r = 0; r < 4; r++)
                red[wave][i * 3 + t][lane][r] = acc[i][t][r];
    __syncthreads();

    float* dst = KV + (size_t)bh * (32 * 33);
    for (int e = tid; e < 6 * 64 * 4; e += 256) {
        const int t = e >> 8, li = (e >> 2) & 63, r = e & 3;
        const float s = red[0][t][li][r] + red[1][t][li][r]
                      + red[2][t][li][r] + red[3][t][li][r];
        const int i = t / 3, j = t % 3;
        const int m = i * 16 + (li >> 4) * 4 + r;
        const int d = j * 16 + (li & 15);
        if (d < 33) atomicAdd(&dst[m * 33 + d], s);
    }
}

// ---------------------------------------------------------------------------
// FAVOR num/den via MFMA, in-place over Q region of fused QKV (stride 768).
// kvT m-stride padded to 40 elems (80 B) to spread bank groups.
// ---------------------------------------------------------------------------
#define KVT_MS 40
__global__ __launch_bounds__(256) void favor_mfma(
    bf16_t* __restrict__ QKV, const float* __restrict__ KV)
{
    __shared__ __align__(16) bf16_t kvT[NHEAD * 48 * KVT_MS];   // 30 KB
    const int blk = blockIdx.x;
    const int b = blk >> 5;
    const int row0 = b * LSEQ + (blk & 31) * 128;
    const int tid = threadIdx.x;

    for (int e = tid; e < NHEAD * 48 * 32; e += 256) {
        const int h = e / (48 * 32);
        const int rem = e - h * (48 * 32);
        const int d = rem >> 5, m = rem & 31;
        bf16_t v = 0;
        if (d < 33) v = f2b(KV[((size_t)(b * NHEAD + h)) * (32 * 33) + m * 33 + d]);
        kvT[(h * 48 + d) * KVT_MS + m] = v;
    }
    __syncthreads();

    const int wave = tid >> 6, lane = tid & 63;
    const int quad = lane >> 4, mr = lane & 15;
    const int wrow0 = row0 + wave * 32;

    for (int h = 0; h < NHEAD; h++) {
        short8 bf[3];
#pragma unroll
        for (int t = 0; t < 3; t++)
            bf[t] = *(const short8*)&kvT[(h * 48 + t * 16 + mr) * KVT_MS + quad * 8];
#pragma unroll
        for (int mt = 0; mt < 2; mt++) {
            const int r0 = wrow0 + mt * 16;
            short8 araw = *(const short8*)(QKV + (size_t)(r0 + mr) * 768 + h * 32 + quad * 8);
            short8 a;
#pragma unroll
            for (int j = 0; j < 8; j++)
                a[j] = (short)f2b(fmaxf(b2f((bf16_t)araw[j]), 0.f) + KEPS_F);
            float4v c0 = __builtin_amdgcn_mfma_f32_16x16x32_bf16(a, bf[0], (float4v)(0.f), 0, 0, 0);
            float4v c1 = __builtin_amdgcn_mfma_f32_16x16x32_bf16(a, bf[1], (float4v)(0.f), 0, 0, 0);
            float4v c2 = __builtin_amdgcn_mfma_f32_16x16x32_bf16(a, bf[2], (float4v)(0.f), 0, 0, 0);
#pragma unroll
            for (int r = 0; r < 4; r++) {
                const float den = __shfl(c2[r], quad << 4);
                const float rinv = 1.0f / den;
                bf16_t* qrow = QKV + (size_t)(r0 + quad * 4 + r) * 768 + h * 32;
                qrow[mr]      = f2b(c0[r] * rinv);
                qrow[16 + mr] = f2b(c1[r] * rinv);
            }
        }
    }
}

// ---------------------------------------------------------------------------
// LayerNorm: one row per WAVE, shfl_xor butterfly; prescale fuses doubling.
// ---------------------------------------------------------------------------
__global__ __launch_bounds__(256) void ln_kernel(
    const bf16_t* __restrict__ in, const float* __restrict__ sc,
    const float* __restrict__ bi, bf16_t* __restrict__ out, float prescale)
{
    const int wave = threadIdx.x >> 6, lane = threadIdx.x & 63;
    const size_t row = (size_t)blockIdx.x * 4 + wave;
    const int c = lane * 4;
    ushort4 raw = *(const ushort4*)(in + row * HIDD + c);
    float v0 = b2f(raw.x) * prescale, v1 = b2f(raw.y) * prescale;
    float v2 = b2f(raw.z) * prescale, v3 = b2f(raw.w) * prescale;
    float s  = v0 + v1 + v2 + v3;
    float s2 = v0 * v0 + v1 * v1 + v2 * v2 + v3 * v3;
#pragma unroll
    for (int off = 1; off < 64; off <<= 1) {
        s  += __shfl_xor(s, off, 64);
        s2 += __shfl_xor(s2, off, 64);
    }
    const float mean = s * (1.0f / 256.0f);
    const float var  = s2 * (1.0f / 256.0f) - mean * mean;
    const float rs = rsqrtf(var + LNEPS_F);
    const float4 scv = *(const float4*)(sc + c);
    const float4 biv = *(const float4*)(bi + c);
    ushort4 o;
    o.x = f2b((v0 - mean) * rs * scv.x + biv.x);
    o.y = f2b((v1 - mean) * rs * scv.y + biv.y);
    o.z = f2b((v2 - mean) * rs * scv.z + biv.z);
    o.w = f2b((v3 - mean) * rs * scv.w + biv.w);
    *(ushort4*)(out + row * HIDD + c) = o;
}

// ---------------------------------------------------------------------------
// Head (fp32 out): out[0:4096] = x[:,0,:] ; out[4096:4608] = x@qpW + qpb
// ---------------------------------------------------------------------------
__global__ __launch_bounds__(256) void head_kernel(
    const bf16_t* __restrict__ X, const float* __restrict__ qpW,
    const float* __restrict__ qpb, float* __restrict__ out)
{
    const int b = blockIdx.x, j = threadIdx.x;
    __shared__ float xr[HIDD];
    float v = b2f(X[((size_t)b * LSEQ) * HIDD + j]);
    xr[j] = v;
    out[b * HIDD + j] = v;
    __syncthreads();
    if (j < 32) {
        float acc = qpb[j];
        for (int d = 0; d < HIDD; d++)
            acc = fmaf(xr[d], qpW[d * 32 + j], acc);
        out[NB * HIDD + b * 32 + j] = acc;
    }
}

// ---------------------------------------------------------------------------
extern "C" void kernel_launch(void* const* d_in, const int* in_sizes, int n_in,
                              void* d_out, int out_size, void* d_ws, size_t ws_size,
                              hipStream_t stream)
{
    const float* hidden = (const float*)d_in[0];
    const float* ins    = (const float*)d_in[1];
    const int*   resets = (const int*)d_in[2];
    const float* embW   = (const float*)d_in[3];
    const float* embb   = (const float*)d_in[4];
    const float* Wq = (const float*)d_in[5];
    const float* bq = (const float*)d_in[6];
    const float* Wk = (const float*)d_in[7];
    const float* bk = (const float*)d_in[8];
    const float* Wv = (const float*)d_in[9];
    const float* bv = (const float*)d_in[10];
    const float* Wo = (const float*)d_in[11];
    const float* bo = (const float*)d_in[12];
    const float* ln1s = (const float*)d_in[13];
    const float* ln1b = (const float*)d_in[14];
    const float* W1 = (const float*)d_in[15];
    const float* b1 = (const float*)d_in[16];
    const float* W2 = (const float*)d_in[17];
    const float* b2 = (const float*)d_in[18];
    const float* ln2s = (const float*)d_in[19];
    const float* ln2b = (const float*)d_in[20];
    const float* qpW = (const float*)d_in[21];
    const float* qpb = (const float*)d_in[22];

    // ---- workspace (~243 MB < 256 MiB) ----
    const size_t ACT_SZ = (size_t)MROWS * HIDD;            // 16.78M elems
    bf16_t* X    = (bf16_t*)d_ws;                          // 33.5 MB
    bf16_t* QKV  = X + ACT_SZ;                             // 65536x768 = 100.7 MB
    bf16_t* T    = QKV + (size_t)MROWS * 768;              // 33.5 MB (Wo/FF2 out)
    bf16_t* H1   = T + ACT_SZ;                             // 32768x1024 = 67 MB
    bf16_t* Ain  = H1;                                     // alias (pre-layer)
    float*  KV   = (float*)(H1 + (size_t)32768 * FFD);     // 0.54 MB
    float*  bqkv = KV + KV_ELEMS;                          // 4x768 f32
    bf16_t* WqkvT = (bf16_t*)(bqkv + NLAY * 768);          // [l][768][256]
    bf16_t* WoT   = WqkvT + (size_t)NLAY * 3 * HIDD * HIDD;
    bf16_t* W1T   = WoT + (size_t)NLAY * HIDD * HIDD;
    bf16_t* W2T   = W1T + (size_t)NLAY * HIDD * FFD;
    bf16_t* embWT = W2T + (size_t)NLAY * FFD * HIDD;

    const dim3 blk(256);
    const size_t HH = (size_t)HIDD * HIDD;

    conv_transpose_kernel<<<dim3(8, 8, NLAY), blk, 0, stream>>>(Wq, WqkvT,          HIDD, HIDD, HH, 3 * HH);
    conv_transpose_kernel<<<dim3(8, 8, NLAY), blk, 0, stream>>>(Wk, WqkvT + HH,     HIDD, HIDD, HH, 3 * HH);
    conv_transpose_kernel<<<dim3(8, 8, NLAY), blk, 0, stream>>>(Wv, WqkvT + 2 * HH, HIDD, HIDD, HH, 3 * HH);
    conv_transpose_kernel<<<dim3(8, 8, NLAY), blk, 0, stream>>>(Wo, WoT, HIDD, HIDD, HH, HH);
    conv_transpose_kernel<<<dim3(32, 8, NLAY), blk, 0, stream>>>(W1, W1T, HIDD, FFD, (size_t)HIDD * FFD, (size_t)HIDD * FFD);
    conv_transpose_kernel<<<dim3(8, 32, NLAY), blk, 0, stream>>>(W2, W2T, FFD, HIDD, (size_t)HIDD * FFD, (size_t)HIDD * FFD);
    conv_transpose_kernel<<<dim3(8, 4, 1), blk, 0, stream>>>(embW, embWT, 128, HIDD, 0, 0);
    concat_bias_kernel<<<NLAY, blk, 0, stream>>>(bq, bk, bv, bqkv);

    prep_a_kernel<<<MROWS / 2, blk, 0, stream>>>(ins, Ain);
    gemm_mfma<0><<<dim3(2, 512), blk, 0, stream>>>(Ain, embWT, embb, X, MROWS, HIDD, 128, 128, HIDD);
    fix_row0_kernel<<<NB, blk, 0, stream>>>(hidden, resets, X);

    for (int l = 0; l < NLAY; l++) {
        gemm_mfma<0><<<dim3(6, 512), blk, 0, stream>>>(X, WqkvT + (size_t)l * 3 * HH,
                                                       bqkv + l * 768, QKV, MROWS, 768, HIDD, HIDD, 768);

        zero_kv<<<(KV_ELEMS + 255) / 256, blk, 0, stream>>>(KV);
        kv_mfma<<<dim3(NB * NHEAD, 8), blk, 0, stream>>>(QKV, KV);
        favor_mfma<<<NB * 32, blk, 0, stream>>>(QKV, KV);

        gemm_mfma<0><<<dim3(2, 512), blk, 0, stream>>>(QKV, WoT + (size_t)l * HH,
                                                       bo + l * HIDD, T, MROWS, HIDD, HIDD, 768, HIDD);
        ln_kernel<<<MROWS / 4, blk, 0, stream>>>(T, ln1s + l * HIDD, ln1b + l * HIDD, X, 2.0f);

        for (int c = 0; c < 2; c++) {
            const size_t off = (size_t)c * 32768;
            gemm_mfma<1><<<dim3(8, 256), blk, 0, stream>>>(X + off * HIDD, W1T + (size_t)l * HIDD * FFD,
                                                           b1 + l * FFD, H1, 32768, FFD, HIDD, HIDD, FFD);
            gemm_mfma<0><<<dim3(2, 256), blk, 0, stream>>>(H1, W2T + (size_t)l * FFD * HIDD,
                                                           b2 + l * HIDD, T + off * HIDD, 32768, HIDD, FFD, FFD, HIDD);
        }
        ln_kernel<<<MROWS / 4, blk, 0, stream>>>(T, ln2s + l * HIDD, ln2b + l * HIDD, X, 2.0f);
    }

    head_kernel<<<NB, blk, 0, stream>>>(X, qpW, qpb, (float*)d_out);
}

// Round 9
// 1278.818 us; speedup vs baseline: 7.9675x; 1.0529x over previous
//
#include <hip/hip_runtime.h>

// ---------------------------------------------------------------------------
// TransformerAgent (Performer/FAVOR+ encoder), MI355X gfx950.
// Round 9: LN fused into the N=256 GEMMs (Wo+LN1, FF2+LN2) via a 512-thread
// 128x256-tile kernel with cross-wave row-stat reduction in LDS. Removes the
// T buffer, 8 ln dispatches and 536 MB of activation round-trips. QKV/FF1/
// embed keep the round-8 swizzled 256-thr gemm. kv/favor unchanged.
// B=16, L=4096(=1+4095), HID=256, NH=8, DH=32, FF=1024, NL=4, ACT=32
// ---------------------------------------------------------------------------

typedef unsigned short bf16_t;
typedef __attribute__((ext_vector_type(8))) short short8;
typedef __attribute__((ext_vector_type(4))) float float4v;

#define NB 16
#define LSEQ 4096
#define MROWS (NB * LSEQ)      // 65536
#define HIDD 256
#define NHEAD 8
#define DHEAD 32
#define FFD 1024
#define NLAY 4
#define KEPS_F 1e-3f
#define LNEPS_F 1e-6f
#define KV_ELEMS (NB * NHEAD * 32 * 33)   // 135168

__device__ __forceinline__ float b2f(bf16_t h) {
    return __uint_as_float(((unsigned int)h) << 16);
}
__device__ __forceinline__ bf16_t f2b(float f) {
    unsigned int u = __float_as_uint(f);
    u += 0x7fffu + ((u >> 16) & 1u);   // round-to-nearest-even
    return (bf16_t)(u >> 16);
}

// async global->LDS, 16B per lane
#define GLOAD_LDS16(g, l)                                                     \
    __builtin_amdgcn_global_load_lds(                                         \
        (const __attribute__((address_space(1))) void*)(g),                   \
        (__attribute__((address_space(3))) void*)(l), 16, 0, 0)

// ---------------------------------------------------------------------------
// Convert+transpose: in[z*ils + R][C] f32 -> out[z*ols + C][R] bf16.
// ---------------------------------------------------------------------------
__global__ __launch_bounds__(256) void conv_transpose_kernel(
    const float* __restrict__ in, bf16_t* __restrict__ out, int R, int C,
    size_t ils, size_t ols)
{
    __shared__ float tile[32][33];
    const size_t ib = (size_t)blockIdx.z * ils;
    const size_t ob = (size_t)blockIdx.z * ols;
    const int r0 = blockIdx.y * 32, c0 = blockIdx.x * 32;
    const int tx = threadIdx.x & 31, ty = threadIdx.x >> 5;   // 32 x 8
#pragma unroll
    for (int rr = ty; rr < 32; rr += 8)
        tile[rr][tx] = in[ib + (size_t)(r0 + rr) * C + c0 + tx];
    __syncthreads();
#pragma unroll
    for (int rr = ty; rr < 32; rr += 8)
        out[ob + (size_t)(c0 + rr) * R + r0 + tx] = f2b(tile[tx][rr]);
}

// concat per-layer q/k/v biases into bqkv[l][768]
__global__ __launch_bounds__(256) void concat_bias_kernel(
    const float* __restrict__ bq, const float* __restrict__ bk,
    const float* __restrict__ bv, float* __restrict__ bqkv)
{
    const int l = blockIdx.x, j = threadIdx.x;
    bqkv[l * 768 + j]       = bq[l * 256 + j];
    bqkv[l * 768 + 256 + j] = bk[l * 256 + j];
    bqkv[l * 768 + 512 + j] = bv[l * 256 + j];
}

// ---------------------------------------------------------------------------
// Embed A-prep: Ain[b*4096+l][128] = (l==0) ? 0 : bf16(ins[b][l-1][:])
// ---------------------------------------------------------------------------
__global__ __launch_bounds__(256) void prep_a_kernel(
    const float* __restrict__ ins, bf16_t* __restrict__ Ain)
{
    const int row = blockIdx.x * 2 + (threadIdx.x >> 7);
    const int j = threadIdx.x & 127;
    const int b = row >> 12, l = row & (LSEQ - 1);
    bf16_t v = 0;
    if (l != 0) v = f2b(ins[((size_t)b * 4095 + (l - 1)) * 128 + j]);
    Ain[(size_t)row * 128 + j] = v;
}

// X[b,0,:] = resets ? 0 : hidden
__global__ __launch_bounds__(256) void fix_row0_kernel(
    const float* __restrict__ hidden, const int* __restrict__ resets,
    bf16_t* __restrict__ X)
{
    const int b = blockIdx.x, j = threadIdx.x;
    float v = resets[b] ? 0.f : hidden[b * HIDD + j];
    X[((size_t)b * LSEQ) * HIDD + j] = f2b(v);
}

// ---------------------------------------------------------------------------
// MFMA GEMM (plain): C = act(A @ W + bias); WT[N][K]. 256 thr, 128x128 tile,
// XOR-swizzled LDS (chunk j of row r at j^(r&7)).
// ---------------------------------------------------------------------------
template <int MODE>
__global__ __launch_bounds__(256) void gemm_mfma(
    const bf16_t* __restrict__ A, const bf16_t* __restrict__ WT,
    const float* __restrict__ bias, bf16_t* __restrict__ C,
    int M, int N, int K, int lda, int ldc)
{
    __shared__ __align__(16) bf16_t As[128 * 64];
    __shared__ __align__(16) bf16_t Bs[128 * 64];
    const int tid = threadIdx.x;
    const int wave = tid >> 6, lane = tid & 63;
    const int bm = blockIdx.y * 128, bn = blockIdx.x * 128;
    const int quad = lane >> 4, mrow = lane & 15;
    const int mxor = mrow & 7;
    const int wm0 = (wave & 1) * 64, wn0 = (wave >> 1) * 64;

    float4v acc[4][4];
#pragma unroll
    for (int i = 0; i < 4; i++)
#pragma unroll
        for (int j = 0; j < 4; j++) acc[i][j] = (float4v)(0.f);

    for (int k0 = 0; k0 < K; k0 += 64) {
#pragma unroll
        for (int is = 0; is < 4; is++) {
            const int c = (wave * 4 + is) * 64 + lane;
            const int r = c >> 3;
            const int kofs = ((c & 7) ^ (r & 7)) * 8;
            GLOAD_LDS16(A  + (size_t)(bm + r) * lda + k0 + kofs, &As[c * 8]);
            GLOAD_LDS16(WT + (size_t)(bn + r) * K   + k0 + kofs, &Bs[c * 8]);
        }
        __syncthreads();
#pragma unroll
        for (int kk = 0; kk < 8; kk += 4) {
            short8 a[4], b[4];
#pragma unroll
            for (int i = 0; i < 4; i++)
                a[i] = *(const short8*)&As[((wm0 + i * 16 + mrow) * 8 + ((quad + kk) ^ mxor)) * 8];
#pragma unroll
            for (int j = 0; j < 4; j++)
                b[j] = *(const short8*)&Bs[((wn0 + j * 16 + mrow) * 8 + ((quad + kk) ^ mxor)) * 8];
#pragma unroll
            for (int i = 0; i < 4; i++)
#pragma unroll
                for (int j = 0; j < 4; j++)
                    acc[i][j] = __builtin_amdgcn_mfma_f32_16x16x32_bf16(
                        a[i], b[j], acc[i][j], 0, 0, 0);
        }
        __syncthreads();
    }

    float bcol[4];
#pragma unroll
    for (int j = 0; j < 4; j++) bcol[j] = bias[bn + wn0 + j * 16 + mrow];
#pragma unroll
    for (int i = 0; i < 4; i++) {
#pragma unroll
        for (int r = 0; r < 4; r++) {
            const int grow = bm + wm0 + i * 16 + quad * 4 + r;
            bf16_t* crow = C + (size_t)grow * ldc + bn + wn0 + mrow;
#pragma unroll
            for (int j = 0; j < 4; j++) {
                float v = acc[i][j][r] + bcol[j];
                if (MODE == 1) v = fmaxf(v, 0.f);
                crow[j * 16] = f2b(v);
            }
        }
    }
}

// ---------------------------------------------------------------------------
// MFMA GEMM + fused LayerNorm epilogue. N=256 fixed (full rows per block).
// out = LN(2*(A@W + bias)) * sc + bi.  512 thr = 8 waves (2 m-halves x 4
// n-quarters of 64x64). Row stats: per-quad shfl reduce -> LDS partials ->
// cross-wave sum. ldc = 256.
// ---------------------------------------------------------------------------
__global__ __launch_bounds__(512) void gemm_ln_mfma(
    const bf16_t* __restrict__ A, const bf16_t* __restrict__ WT,
    const float* __restrict__ bias, const float* __restrict__ sc,
    const float* __restrict__ bi, bf16_t* __restrict__ out,
    int K, int lda)
{
    __shared__ __align__(16) bf16_t As[128 * 64];   // 16 KB
    __shared__ __align__(16) bf16_t Bs[256 * 64];   // 32 KB
    __shared__ float red[8][64][2];                 // 4 KB
    __shared__ float fin[128][2];                   // 1 KB

    const int tid = threadIdx.x;
    const int wave = tid >> 6, lane = tid & 63;
    const int bm = blockIdx.x * 128;
    const int quad = lane >> 4, mr = lane & 15;
    const int mxor = mr & 7;
    const int wm0 = (wave & 1) * 64;       // m-half
    const int wn0 = (wave >> 1) * 64;      // n-quarter

    float4v acc[4][4];
#pragma unroll
    for (int i = 0; i < 4; i++)
#pragma unroll
        for (int j = 0; j < 4; j++) acc[i][j] = (float4v)(0.f);

    for (int k0 = 0; k0 < K; k0 += 64) {
#pragma unroll
        for (int it = 0; it < 6; it++) {
            const int c = it * 512 + tid;           // 0..3071 (wave-uniform branch)
            if (c < 1024) {
                const int r = c >> 3;
                const int kofs = ((c & 7) ^ (r & 7)) * 8;
                GLOAD_LDS16(A + (size_t)(bm + r) * lda + k0 + kofs, &As[c * 8]);
            } else {
                const int cb = c - 1024;
                const int r = cb >> 3;
                const int kofs = ((cb & 7) ^ (r & 7)) * 8;
                GLOAD_LDS16(WT + (size_t)r * K + k0 + kofs, &Bs[cb * 8]);
            }
        }
        __syncthreads();
#pragma unroll
        for (int kk = 0; kk < 8; kk += 4) {
            short8 a[4], b[4];
#pragma unroll
            for (int i = 0; i < 4; i++)
                a[i] = *(const short8*)&As[((wm0 + i * 16 + mr) * 8 + ((quad + kk) ^ mxor)) * 8];
#pragma unroll
            for (int j = 0; j < 4; j++)
                b[j] = *(const short8*)&Bs[((wn0 + j * 16 + mr) * 8 + ((quad + kk) ^ mxor)) * 8];
#pragma unroll
            for (int i = 0; i < 4; i++)
#pragma unroll
                for (int j = 0; j < 4; j++)
                    acc[i][j] = __builtin_amdgcn_mfma_f32_16x16x32_bf16(
                        a[i], b[j], acc[i][j], 0, 0, 0);
        }
        __syncthreads();
    }

    float bcol[4];
#pragma unroll
    for (int j = 0; j < 4; j++) bcol[j] = bias[wn0 + j * 16 + mr];

    // row partial sums over this wave's 64 cols (reduce across mr in-quad)
#pragma unroll
    for (int i = 0; i < 4; i++) {
#pragma unroll
        for (int r = 0; r < 4; r++) {
            float s = 0.f, s2 = 0.f;
#pragma unroll
            for (int j = 0; j < 4; j++) {
                const float v = 2.0f * (acc[i][j][r] + bcol[j]);
                s += v; s2 += v * v;
            }
#pragma unroll
            for (int off = 1; off < 16; off <<= 1) {
                s  += __shfl_xor(s, off, 64);
                s2 += __shfl_xor(s2, off, 64);
            }
            if (mr == 0) {
                const int rl = i * 16 + quad * 4 + r;
                red[wave][rl][0] = s;
                red[wave][rl][1] = s2;
            }
        }
    }
    __syncthreads();
    if (tid < 256) {
        const int R = tid >> 1, p = tid & 1;
        const int mh = R >> 6, rl = R & 63;
        fin[R][p] = red[mh][rl][p] + red[mh + 2][rl][p]
                  + red[mh + 4][rl][p] + red[mh + 6][rl][p];
    }
    __syncthreads();

    float scv[4], biv[4];
#pragma unroll
    for (int j = 0; j < 4; j++) {
        scv[j] = sc[wn0 + j * 16 + mr];
        biv[j] = bi[wn0 + j * 16 + mr];
    }
#pragma unroll
    for (int i = 0; i < 4; i++) {
#pragma unroll
        for (int r = 0; r < 4; r++) {
            const int R = wm0 + i * 16 + quad * 4 + r;
            const float mean = fin[R][0] * (1.0f / 256.0f);
            const float var  = fin[R][1] * (1.0f / 256.0f) - mean * mean;
            const float rs = rsqrtf(var + LNEPS_F);
            bf16_t* crow = out + (size_t)(bm + R) * 256 + wn0 + mr;
#pragma unroll
            for (int j = 0; j < 4; j++) {
                const float v = 2.0f * (acc[i][j][r] + bcol[j]);
                crow[j * 16] = f2b((v - mean) * rs * scv[j] + biv[j]);
            }
        }
    }
}

// ---------------------------------------------------------------------------
// Zero the KV accumulator
// ---------------------------------------------------------------------------
__global__ __launch_bounds__(256) void zero_kv(float* __restrict__ KV)
{
    int i = blockIdx.x * 256 + threadIdx.x;
    if (i < KV_ELEMS) KV[i] = 0.f;
}

// ---------------------------------------------------------------------------
// FAVOR kv state via MFMA. Per (b,h): KV[32x33] = kp^T[32xL] @ [V|1][Lx33].
// ---------------------------------------------------------------------------
__global__ __launch_bounds__(256) void kv_mfma(
    const bf16_t* __restrict__ QKV, float* __restrict__ KV)
{
    __shared__ __align__(16) char smem[24576];
    bf16_t (*kp)[36] = (bf16_t(*)[36])smem;                 // 128x36x2 = 9216 B
    bf16_t (*vv)[52] = (bf16_t(*)[52])(smem + 9216);        // 128x52x2 = 13312 B
    float (*red)[6][64][4] = (float(*)[6][64][4])smem;      // 24576 B (aliases)

    const int bh = blockIdx.x;
    const int b = bh >> 3, h = bh & 7;
    const size_t rowbase = (size_t)b * LSEQ + blockIdx.y * 512;
    const int tid = threadIdx.x;
    const int wave = tid >> 6, lane = tid & 63;
    const int quad = lane >> 4, mr = lane & 15;

    for (int e = tid; e < 128 * 20; e += 256) {
        const int l = e / 20, c = 32 + (e % 20);
        vv[l][c] = (c == 32) ? (bf16_t)0x3F80 : (bf16_t)0;
    }

    float4v acc[2][3];
#pragma unroll
    for (int i = 0; i < 2; i++)
#pragma unroll
        for (int t = 0; t < 3; t++) acc[i][t] = (float4v)(0.f);

    for (int pass = 0; pass < 4; pass++) {
        __syncthreads();
        const size_t lp = rowbase + pass * 128;
#pragma unroll
        for (int it = 0; it < 4; it++) {
            const int e = tid + it * 256;
            const int l = e >> 3, c0 = (e & 7) * 4;
            const bf16_t* src = QKV + (lp + l) * 768 + 256 + h * 32 + c0;
            ushort4 kq = *(const ushort4*)src;
            ushort4 vq = *(const ushort4*)(src + 256);
            ushort4 ko;
            ko.x = f2b(fmaxf(b2f(kq.x), 0.f) + KEPS_F);
            ko.y = f2b(fmaxf(b2f(kq.y), 0.f) + KEPS_F);
            ko.z = f2b(fmaxf(b2f(kq.z), 0.f) + KEPS_F);
            ko.w = f2b(fmaxf(b2f(kq.w), 0.f) + KEPS_F);
            *(ushort4*)&kp[l][c0] = ko;
            *(ushort4*)&vv[l][c0] = vq;
        }
        __syncthreads();

        const int lw = wave * 32 + quad * 8;
        short8 a[2], bb[3];
#pragma unroll
        for (int i = 0; i < 2; i++)
#pragma unroll
            for (int j = 0; j < 8; j++)
                a[i][j] = (short)kp[lw + j][i * 16 + mr];
#pragma unroll
        for (int t = 0; t < 3; t++)
#pragma unroll
            for (int j = 0; j < 8; j++)
                bb[t][j] = (short)vv[lw + j][t * 16 + mr];
#pragma unroll
        for (int i = 0; i < 2; i++)
#pragma unroll
            for (int t = 0; t < 3; t++)
                acc[i][t] = __builtin_amdgcn_mfma_f32_16x16x32_bf16(
                    a[i], bb[t], acc[i][t], 0, 0, 0);
    }

    __syncthreads();
#pragma unroll
    for (int i = 0; i < 2; i++)
#pragma unroll
        for (int t = 0; t < 3; t++)
#pragma unroll
            for (int r = 0; r < 4; r++)
                red[wave][i * 3 + t][lane][r] = acc[i][t][r];
    __syncthreads();

    float* dst = KV + (size_t)bh * (32 * 33);
    for (int e = tid; e < 6 * 64 * 4; e += 256) {
        const int t = e >> 8, li = (e >> 2) & 63, r = e & 3;
        const float s = red[0][t][li][r] + red[1][t][li][r]
                      + red[2][t][li][r] + red[3][t][li][r];
        const int i = t / 3, j = t % 3;
        const int m = i * 16 + (li >> 4) * 4 + r;
        const int d = j * 16 + (li & 15);
        if (d < 33) atomicAdd(&dst[m * 33 + d], s);
    }
}

// ---------------------------------------------------------------------------
// FAVOR num/den via MFMA, in-place over Q region of fused QKV (stride 768).
// ---------------------------------------------------------------------------
#define KVT_MS 40
__global__ __launch_bounds__(256) void favor_mfma(
    bf16_t* __restrict__ QKV, const float* __restrict__ KV)
{
    __shared__ __align__(16) bf16_t kvT[NHEAD * 48 * KVT_MS];   // 30 KB
    const int blk = blockIdx.x;
    const int b = blk >> 5;
    const int row0 = b * LSEQ + (blk & 31) * 128;
    const int tid = threadIdx.x;

    for (int e = tid; e < NHEAD * 48 * 32; e += 256) {
        const int h = e / (48 * 32);
        const int rem = e - h * (48 * 32);
        const int d = rem >> 5, m = rem & 31;
        bf16_t v = 0;
        if (d < 33) v = f2b(KV[((size_t)(b * NHEAD + h)) * (32 * 33) + m * 33 + d]);
        kvT[(h * 48 + d) * KVT_MS + m] = v;
    }
    __syncthreads();

    const int wave = tid >> 6, lane = tid & 63;
    const int quad = lane >> 4, mr = lane & 15;
    const int wrow0 = row0 + wave * 32;

    for (int h = 0; h < NHEAD; h++) {
        short8 bf[3];
#pragma unroll
        for (int t = 0; t < 3; t++)
            bf[t] = *(const short8*)&kvT[(h * 48 + t * 16 + mr) * KVT_MS + quad * 8];
#pragma unroll
        for (int mt = 0; mt < 2; mt++) {
            const int r0 = wrow0 + mt * 16;
            short8 araw = *(const short8*)(QKV + (size_t)(r0 + mr) * 768 + h * 32 + quad * 8);
            short8 a;
#pragma unroll
            for (int j = 0; j < 8; j++)
                a[j] = (short)f2b(fmaxf(b2f((bf16_t)araw[j]), 0.f) + KEPS_F);
            float4v c0 = __builtin_amdgcn_mfma_f32_16x16x32_bf16(a, bf[0], (float4v)(0.f), 0, 0, 0);
            float4v c1 = __builtin_amdgcn_mfma_f32_16x16x32_bf16(a, bf[1], (float4v)(0.f), 0, 0, 0);
            float4v c2 = __builtin_amdgcn_mfma_f32_16x16x32_bf16(a, bf[2], (float4v)(0.f), 0, 0, 0);
#pragma unroll
            for (int r = 0; r < 4; r++) {
                const float den = __shfl(c2[r], quad << 4);
                const float rinv = 1.0f / den;
                bf16_t* qrow = QKV + (size_t)(r0 + quad * 4 + r) * 768 + h * 32;
                qrow[mr]      = f2b(c0[r] * rinv);
                qrow[16 + mr] = f2b(c1[r] * rinv);
            }
        }
    }
}

// ---------------------------------------------------------------------------
// Head (fp32 out): out[0:4096] = x[:,0,:] ; out[4096:4608] = x@qpW + qpb
// ---------------------------------------------------------------------------
__global__ __launch_bounds__(256) void head_kernel(
    const bf16_t* __restrict__ X, const float* __restrict__ qpW,
    const float* __restrict__ qpb, float* __restrict__ out)
{
    const int b = blockIdx.x, j = threadIdx.x;
    __shared__ float xr[HIDD];
    float v = b2f(X[((size_t)b * LSEQ) * HIDD + j]);
    xr[j] = v;
    out[b * HIDD + j] = v;
    __syncthreads();
    if (j < 32) {
        float acc = qpb[j];
        for (int d = 0; d < HIDD; d++)
            acc = fmaf(xr[d], qpW[d * 32 + j], acc);
        out[NB * HIDD + b * 32 + j] = acc;
    }
}

// ---------------------------------------------------------------------------
extern "C" void kernel_launch(void* const* d_in, const int* in_sizes, int n_in,
                              void* d_out, int out_size, void* d_ws, size_t ws_size,
                              hipStream_t stream)
{
    const float* hidden = (const float*)d_in[0];
    const float* ins    = (const float*)d_in[1];
    const int*   resets = (const int*)d_in[2];
    const float* embW   = (const float*)d_in[3];
    const float* embb   = (const float*)d_in[4];
    const float* Wq = (const float*)d_in[5];
    const float* bq = (const float*)d_in[6];
    const float* Wk = (const float*)d_in[7];
    const float* bk = (const float*)d_in[8];
    const float* Wv = (const float*)d_in[9];
    const float* bv = (const float*)d_in[10];
    const float* Wo = (const float*)d_in[11];
    const float* bo = (const float*)d_in[12];
    const float* ln1s = (const float*)d_in[13];
    const float* ln1b = (const float*)d_in[14];
    const float* W1 = (const float*)d_in[15];
    const float* b1 = (const float*)d_in[16];
    const float* W2 = (const float*)d_in[17];
    const float* b2 = (const float*)d_in[18];
    const float* ln2s = (const float*)d_in[19];
    const float* ln2b = (const float*)d_in[20];
    const float* qpW = (const float*)d_in[21];
    const float* qpb = (const float*)d_in[22];

    // ---- workspace (~210 MB < 256 MiB) ----
    const size_t ACT_SZ = (size_t)MROWS * HIDD;            // 16.78M elems
    bf16_t* X    = (bf16_t*)d_ws;                          // 33.5 MB
    bf16_t* QKV  = X + ACT_SZ;                             // 65536x768 = 100.7 MB
    bf16_t* H1   = QKV + (size_t)MROWS * 768;              // 32768x1024 = 67 MB
    bf16_t* Ain  = H1;                                     // alias (pre-layer)
    float*  KV   = (float*)(H1 + (size_t)32768 * FFD);     // 0.54 MB
    float*  bqkv = KV + KV_ELEMS;                          // 4x768 f32
    bf16_t* WqkvT = (bf16_t*)(bqkv + NLAY * 768);          // [l][768][256]
    bf16_t* WoT   = WqkvT + (size_t)NLAY * 3 * HIDD * HIDD;
    bf16_t* W1T   = WoT + (size_t)NLAY * HIDD * HIDD;
    bf16_t* W2T   = W1T + (size_t)NLAY * HIDD * FFD;
    bf16_t* embWT = W2T + (size_t)NLAY * FFD * HIDD;

    const dim3 blk(256);
    const size_t HH = (size_t)HIDD * HIDD;

    conv_transpose_kernel<<<dim3(8, 8, NLAY), blk, 0, stream>>>(Wq, WqkvT,          HIDD, HIDD, HH, 3 * HH);
    conv_transpose_kernel<<<dim3(8, 8, NLAY), blk, 0, stream>>>(Wk, WqkvT + HH,     HIDD, HIDD, HH, 3 * HH);
    conv_transpose_kernel<<<dim3(8, 8, NLAY), blk, 0, stream>>>(Wv, WqkvT + 2 * HH, HIDD, HIDD, HH, 3 * HH);
    conv_transpose_kernel<<<dim3(8, 8, NLAY), blk, 0, stream>>>(Wo, WoT, HIDD, HIDD, HH, HH);
    conv_transpose_kernel<<<dim3(32, 8, NLAY), blk, 0, stream>>>(W1, W1T, HIDD, FFD, (size_t)HIDD * FFD, (size_t)HIDD * FFD);
    conv_transpose_kernel<<<dim3(8, 32, NLAY), blk, 0, stream>>>(W2, W2T, FFD, HIDD, (size_t)HIDD * FFD, (size_t)HIDD * FFD);
    conv_transpose_kernel<<<dim3(8, 4, 1), blk, 0, stream>>>(embW, embWT, 128, HIDD, 0, 0);
    concat_bias_kernel<<<NLAY, blk, 0, stream>>>(bq, bk, bv, bqkv);

    prep_a_kernel<<<MROWS / 2, blk, 0, stream>>>(ins, Ain);
    gemm_mfma<0><<<dim3(2, 512), blk, 0, stream>>>(Ain, embWT, embb, X, MROWS, HIDD, 128, 128, HIDD);
    fix_row0_kernel<<<NB, blk, 0, stream>>>(hidden, resets, X);

    for (int l = 0; l < NLAY; l++) {
        gemm_mfma<0><<<dim3(6, 512), blk, 0, stream>>>(X, WqkvT + (size_t)l * 3 * HH,
                                                       bqkv + l * 768, QKV, MROWS, 768, HIDD, HIDD, 768);

        zero_kv<<<(KV_ELEMS + 255) / 256, blk, 0, stream>>>(KV);
        kv_mfma<<<dim3(NB * NHEAD, 8), blk, 0, stream>>>(QKV, KV);
        favor_mfma<<<NB * 32, blk, 0, stream>>>(QKV, KV);

        // Wo + residual-doubling + LN1 fused -> X
        gemm_ln_mfma<<<MROWS / 128, dim3(512), 0, stream>>>(
            QKV, WoT + (size_t)l * HH, bo + l * HIDD,
            ln1s + l * HIDD, ln1b + l * HIDD, X, HIDD, 768);

        for (int c = 0; c < 2; c++) {
            const size_t off = (size_t)c * 32768;
            gemm_mfma<1><<<dim3(8, 256), blk, 0, stream>>>(X + off * HIDD, W1T + (size_t)l * HIDD * FFD,
                                                           b1 + l * FFD, H1, 32768, FFD, HIDD, HIDD, FFD);
            // FF2 + residual-doubling + LN2 fused -> X chunk
            gemm_ln_mfma<<<32768 / 128, dim3(512), 0, stream>>>(
                H1, W2T + (size_t)l * FFD * HIDD, b2 + l * HIDD,
                ln2s + l * HIDD, ln2b + l * HIDD, X + off * HIDD, FFD, FFD);
        }
    }

    head_kernel<<<NB, blk, 0, stream>>>(X, qpW, qpb, (float*)d_out);
}